// Round 1
// baseline (927.214 us; speedup 1.0000x reference)
//
#include <hip/hip_runtime.h>
#include <hip/hip_bf16.h>

#define NN 1024
#define DD 256
#define LL 6

typedef __attribute__((ext_vector_type(8))) short bf16x8;
typedef __attribute__((ext_vector_type(4))) float f32x4;

__device__ __forceinline__ unsigned short f2bf(float f) {
    union { float f; unsigned u; } x; x.f = f;
    return (unsigned short)((x.u + 0x7fffu + ((x.u >> 16) & 1u)) >> 16);
}

__device__ __forceinline__ f32x4 mfma16(bf16x8 a, bf16x8 b, f32x4 c) {
    return __builtin_amdgcn_mfma_f32_16x16x32_bf16(a, b, c, 0, 0, 0);
}

// ---------------- weight fp32 -> bf16 conversion ----------------
__global__ void wconv_kernel(const float* __restrict__ Wq, const float* __restrict__ Wk,
                             const float* __restrict__ Wv, const float* __restrict__ Wm,
                             const float* __restrict__ W1, const float* __restrict__ W2,
                             unsigned short* __restrict__ dst) {
    const int SQ = LL * 65536;       // 393216
    const int S1 = LL * 262144;      // 1572864
    const int S2 = LL * 131072;      // 786432
    int idx = blockIdx.x * 256 + threadIdx.x;
    int total = 4 * SQ + S1 + S2;
    if (idx >= total) return;
    float v;
    if (idx < 4 * SQ) {
        int seg = idx / SQ, off = idx % SQ;
        const float* p = (seg == 0) ? Wq : (seg == 1) ? Wk : (seg == 2) ? Wv : Wm;
        v = p[off];
    } else if (idx < 4 * SQ + S1) {
        v = W1[idx - 4 * SQ];
    } else {
        v = W2[idx - 4 * SQ - S1];
    }
    dst[idx] = f2bf(v);
}

// ---------------- init: transpose [2][256][1024] -> [4][1024][256] ----------------
__global__ void init_kernel(const float* __restrict__ desc0, const float* __restrict__ desc1,
                            float* __restrict__ desc, unsigned short* __restrict__ xbf) {
    int idx = blockIdx.x * 256 + threadIdx.x;   // 4*1024*256 = 1M
    int c = idx & 255, n = (idx >> 8) & 1023, bb = idx >> 18;
    const float* src = (bb < 2) ? (desc0 + ((size_t)bb * DD + c) * NN + n)
                                : (desc1 + ((size_t)(bb - 2) * DD + c) * NN + n);
    float v = *src;
    desc[idx] = v;
    xbf[idx] = f2bf(v);
}

// ---------------- final: transpose [4][1024][256] -> [4][256][1024] ----------------
__global__ void final_kernel(const float* __restrict__ desc, float* __restrict__ out) {
    int idx = blockIdx.x * 256 + threadIdx.x;   // 1M
    int n = idx & 1023, c = (idx >> 10) & 255, bb = idx >> 18;
    out[idx] = desc[((size_t)bb * NN + n) * DD + c];
}

// ---------------- q/k/v projections ----------------
// q,k -> [bh][n][d] bf16 ; v -> [bh][d][n] bf16
__global__ __launch_bounds__(256) void proj_kernel(
    const unsigned short* __restrict__ xbf,
    const unsigned short* __restrict__ Wq_l, const unsigned short* __restrict__ Wk_l,
    const unsigned short* __restrict__ Wv_l,
    const float* __restrict__ bq_l, const float* __restrict__ bk_l,
    const float* __restrict__ bv_l,
    unsigned short* __restrict__ qb, unsigned short* __restrict__ kb,
    unsigned short* __restrict__ vb, int cross) {
    int z = blockIdx.z;
    int bb = z / 3, mat = z % 3;
    int srcbb = (mat == 0) ? bb : (cross ? (bb ^ 2) : bb);
    const unsigned short* A = xbf + (size_t)srcbb * NN * DD;
    const unsigned short* W = (mat == 0) ? Wq_l : (mat == 1) ? Wk_l : Wv_l;
    const float* bias = (mat == 0) ? bq_l : (mat == 1) ? bk_l : bv_l;
    int n0 = blockIdx.x * 128, o0 = blockIdx.y * 64;
    int w = threadIdx.x >> 6, lane = threadIdx.x & 63, quad = lane >> 4, l15 = lane & 15;
    int wrow = (w & 1) * 64, wcol = (w >> 1) * 32;
    f32x4 acc[4][2];
#pragma unroll
    for (int r = 0; r < 4; r++)
#pragma unroll
        for (int c = 0; c < 2; c++) acc[r][c] = (f32x4){0.f, 0.f, 0.f, 0.f};
    for (int kk = 0; kk < DD; kk += 32) {
        bf16x8 bf[2], af[4];
#pragma unroll
        for (int cs = 0; cs < 2; cs++)
            bf[cs] = *(const bf16x8*)(W + (size_t)(o0 + wcol + cs * 16 + l15) * DD + kk + quad * 8);
#pragma unroll
        for (int rs = 0; rs < 4; rs++)
            af[rs] = *(const bf16x8*)(A + (size_t)(n0 + wrow + rs * 16 + l15) * DD + kk + quad * 8);
#pragma unroll
        for (int rs = 0; rs < 4; rs++)
#pragma unroll
            for (int cs = 0; cs < 2; cs++)
                acc[rs][cs] = mfma16(af[rs], bf[cs], acc[rs][cs]);
    }
#pragma unroll
    for (int rs = 0; rs < 4; rs++)
#pragma unroll
        for (int cs = 0; cs < 2; cs++)
#pragma unroll
            for (int reg = 0; reg < 4; reg++) {
                int n = n0 + wrow + rs * 16 + quad * 4 + reg;
                int o = o0 + wcol + cs * 16 + l15;
                float val = acc[rs][cs][reg] + bias[o];
                int h = o & 3, d = o >> 2;
                if (mat < 2) {
                    unsigned short* dst = (mat == 0) ? qb : kb;
                    dst[((size_t)(bb * 4 + h) * NN + n) * 64 + d] = f2bf(val);
                } else {
                    vb[((size_t)(bb * 4 + h) * 64 + d) * NN + n] = f2bf(val);
                }
            }
}

// ---------------- flash attention per (b,h) ----------------
__global__ __launch_bounds__(256) void flash_kernel(
    const unsigned short* __restrict__ qb, const unsigned short* __restrict__ kb,
    const unsigned short* __restrict__ vb,
    const float* __restrict__ M0, const float* __restrict__ M1,
    unsigned short* __restrict__ xattn) {
    int bh = blockIdx.y;              // 0..15
    int bb = bh >> 2, h = bh & 3;
    int nb = blockIdx.x;              // 0..15
    int w = threadIdx.x >> 6, lane = threadIdx.x & 63, quad = lane >> 4, l15 = lane & 15;
    const float* mask = (bb < 2) ? (M0 + (size_t)bb * NN * NN) : (M1 + (size_t)(bb - 2) * NN * NN);
    const unsigned short* Q = qb + (size_t)bh * NN * 64;
    const unsigned short* Kb = kb + (size_t)bh * NN * 64;
    const unsigned short* Vb = vb + (size_t)bh * 64 * NN;
    int row0 = nb * 64 + w * 16;

    bf16x8 qf[2];
#pragma unroll
    for (int kc = 0; kc < 2; kc++)
        qf[kc] = *(const bf16x8*)(Q + (size_t)(row0 + l15) * 64 + kc * 32 + quad * 8);

    __shared__ __align__(16) unsigned short Plds[4][16][72];   // per-wave P tile, padded

    f32x4 Oa[4];
#pragma unroll
    for (int dt = 0; dt < 4; dt++) Oa[dt] = (f32x4){0.f, 0.f, 0.f, 0.f};
    float mrun[4], lrun[4];
#pragma unroll
    for (int r = 0; r < 4; r++) { mrun[r] = -1e30f; lrun[r] = 0.f; }

    for (int mt = 0; mt < 16; mt++) {
        int m0 = mt * 64;
        f32x4 s[4];
#pragma unroll
        for (int t = 0; t < 4; t++) s[t] = (f32x4){0.f, 0.f, 0.f, 0.f};
#pragma unroll
        for (int t = 0; t < 4; t++)
#pragma unroll
            for (int kc = 0; kc < 2; kc++) {
                bf16x8 kf = *(const bf16x8*)(Kb + (size_t)(m0 + t * 16 + l15) * 64 + kc * 32 + quad * 8);
                s[t] = mfma16(qf[kc], kf, s[t]);
            }
        float sv[4][4], rmax[4];
#pragma unroll
        for (int r = 0; r < 4; r++) rmax[r] = -1e30f;
#pragma unroll
        for (int t = 0; t < 4; t++)
#pragma unroll
            for (int reg = 0; reg < 4; reg++) {
                int n = row0 + quad * 4 + reg;
                int m = m0 + t * 16 + l15;
                float v = s[t][reg] * 0.125f * mask[(size_t)n * NN + m];
                sv[t][reg] = v;
                rmax[reg] = fmaxf(rmax[reg], v);
            }
#pragma unroll
        for (int reg = 0; reg < 4; reg++) {
            rmax[reg] = fmaxf(rmax[reg], __shfl_xor(rmax[reg], 1, 64));
            rmax[reg] = fmaxf(rmax[reg], __shfl_xor(rmax[reg], 2, 64));
            rmax[reg] = fmaxf(rmax[reg], __shfl_xor(rmax[reg], 4, 64));
            rmax[reg] = fmaxf(rmax[reg], __shfl_xor(rmax[reg], 8, 64));
        }
        float alpha[4], rsum[4];
#pragma unroll
        for (int reg = 0; reg < 4; reg++) {
            float mn = fmaxf(mrun[reg], rmax[reg]);
            alpha[reg] = __expf(mrun[reg] - mn);
            mrun[reg] = mn;
            rsum[reg] = 0.f;
        }
#pragma unroll
        for (int t = 0; t < 4; t++)
#pragma unroll
            for (int reg = 0; reg < 4; reg++) {
                float p = __expf(sv[t][reg] - mrun[reg]);
                sv[t][reg] = p;
                rsum[reg] += p;
            }
#pragma unroll
        for (int reg = 0; reg < 4; reg++) {
            rsum[reg] += __shfl_xor(rsum[reg], 1, 64);
            rsum[reg] += __shfl_xor(rsum[reg], 2, 64);
            rsum[reg] += __shfl_xor(rsum[reg], 4, 64);
            rsum[reg] += __shfl_xor(rsum[reg], 8, 64);
            lrun[reg] = lrun[reg] * alpha[reg] + rsum[reg];
        }
#pragma unroll
        for (int dt = 0; dt < 4; dt++)
#pragma unroll
            for (int reg = 0; reg < 4; reg++) Oa[dt][reg] *= alpha[reg];
        // P -> LDS (C-layout to A-layout transpose)
#pragma unroll
        for (int t = 0; t < 4; t++)
#pragma unroll
            for (int reg = 0; reg < 4; reg++)
                Plds[w][quad * 4 + reg][t * 16 + l15] = f2bf(sv[t][reg]);
        __syncthreads();
        bf16x8 pf[2];
#pragma unroll
        for (int kc = 0; kc < 2; kc++)
            pf[kc] = *(const bf16x8*)(&Plds[w][l15][kc * 32 + quad * 8]);
#pragma unroll
        for (int dt = 0; dt < 4; dt++)
#pragma unroll
            for (int kc = 0; kc < 2; kc++) {
                bf16x8 vf = *(const bf16x8*)(Vb + (size_t)(dt * 16 + l15) * NN + m0 + kc * 32 + quad * 8);
                Oa[dt] = mfma16(pf[kc], vf, Oa[dt]);
            }
        __syncthreads();
    }
#pragma unroll
    for (int dt = 0; dt < 4; dt++)
#pragma unroll
        for (int reg = 0; reg < 4; reg++) {
            int n = row0 + quad * 4 + reg;
            int d = dt * 16 + l15;
            float val = Oa[dt][reg] / lrun[reg];
            xattn[((size_t)bb * NN + n) * DD + d * 4 + h] = f2bf(val);
        }
}

// ---------------- merge conv ----------------
__global__ __launch_bounds__(256) void merge_kernel(
    const unsigned short* __restrict__ xattn, const unsigned short* __restrict__ Wm_l,
    const float* __restrict__ bm_l, unsigned short* __restrict__ ymsg) {
    int bb = blockIdx.z;
    const unsigned short* A = xattn + (size_t)bb * NN * DD;
    int n0 = blockIdx.x * 128, o0 = blockIdx.y * 64;
    int w = threadIdx.x >> 6, lane = threadIdx.x & 63, quad = lane >> 4, l15 = lane & 15;
    int wrow = (w & 1) * 64, wcol = (w >> 1) * 32;
    f32x4 acc[4][2];
#pragma unroll
    for (int r = 0; r < 4; r++)
#pragma unroll
        for (int c = 0; c < 2; c++) acc[r][c] = (f32x4){0.f, 0.f, 0.f, 0.f};
    for (int kk = 0; kk < DD; kk += 32) {
        bf16x8 bf[2], af[4];
#pragma unroll
        for (int cs = 0; cs < 2; cs++)
            bf[cs] = *(const bf16x8*)(Wm_l + (size_t)(o0 + wcol + cs * 16 + l15) * DD + kk + quad * 8);
#pragma unroll
        for (int rs = 0; rs < 4; rs++)
            af[rs] = *(const bf16x8*)(A + (size_t)(n0 + wrow + rs * 16 + l15) * DD + kk + quad * 8);
#pragma unroll
        for (int rs = 0; rs < 4; rs++)
#pragma unroll
            for (int cs = 0; cs < 2; cs++)
                acc[rs][cs] = mfma16(af[rs], bf[cs], acc[rs][cs]);
    }
#pragma unroll
    for (int rs = 0; rs < 4; rs++)
#pragma unroll
        for (int cs = 0; cs < 2; cs++)
#pragma unroll
            for (int reg = 0; reg < 4; reg++) {
                int n = n0 + wrow + rs * 16 + quad * 4 + reg;
                int o = o0 + wcol + cs * 16 + l15;
                ymsg[((size_t)bb * NN + n) * DD + o] = f2bf(acc[rs][cs][reg] + bm_l[o]);
            }
}

// ---------------- conv W1 (concat[x,msg] as split-K A) ----------------
__global__ __launch_bounds__(256) void conv1_kernel(
    const unsigned short* __restrict__ xbf, const unsigned short* __restrict__ ymsg,
    const unsigned short* __restrict__ W1_l, const float* __restrict__ b1_l,
    float* __restrict__ out1) {
    int bb = blockIdx.z;
    const unsigned short* A1 = xbf + (size_t)bb * NN * DD;
    const unsigned short* A2 = ymsg + (size_t)bb * NN * DD;
    int n0 = blockIdx.x * 128, o0 = blockIdx.y * 64;
    int w = threadIdx.x >> 6, lane = threadIdx.x & 63, quad = lane >> 4, l15 = lane & 15;
    int wrow = (w & 1) * 64, wcol = (w >> 1) * 32;
    f32x4 acc[4][2];
#pragma unroll
    for (int r = 0; r < 4; r++)
#pragma unroll
        for (int c = 0; c < 2; c++) acc[r][c] = (f32x4){0.f, 0.f, 0.f, 0.f};
    for (int kk = 0; kk < 512; kk += 32) {
        const unsigned short* As = (kk < 256) ? A1 : A2;
        int kl = kk & 255;
        bf16x8 bf[2], af[4];
#pragma unroll
        for (int cs = 0; cs < 2; cs++)
            bf[cs] = *(const bf16x8*)(W1_l + (size_t)(o0 + wcol + cs * 16 + l15) * 512 + kk + quad * 8);
#pragma unroll
        for (int rs = 0; rs < 4; rs++)
            af[rs] = *(const bf16x8*)(As + (size_t)(n0 + wrow + rs * 16 + l15) * DD + kl + quad * 8);
#pragma unroll
        for (int rs = 0; rs < 4; rs++)
#pragma unroll
            for (int cs = 0; cs < 2; cs++)
                acc[rs][cs] = mfma16(af[rs], bf[cs], acc[rs][cs]);
    }
#pragma unroll
    for (int rs = 0; rs < 4; rs++)
#pragma unroll
        for (int cs = 0; cs < 2; cs++)
#pragma unroll
            for (int reg = 0; reg < 4; reg++) {
                int n = n0 + wrow + rs * 16 + quad * 4 + reg;
                int o = o0 + wcol + cs * 16 + l15;
                out1[((size_t)bb * NN + n) * 512 + o] = acc[rs][cs][reg] + b1_l[o];
            }
}

// ---------------- BN stats: one block per channel ----------------
__global__ __launch_bounds__(256) void bnstats_kernel(
    const float* __restrict__ out1, const float* __restrict__ g1_l,
    const float* __restrict__ beta1_l, float* __restrict__ bnsc, float* __restrict__ bnsh) {
    int o = blockIdx.x;
    int t = threadIdx.x;
    float s = 0.f, s2 = 0.f;
    for (int i = t; i < 4096; i += 256) {
        float v = out1[(size_t)i * 512 + o];
        s += v; s2 += v * v;
    }
    __shared__ float ls[256], ls2[256];
    ls[t] = s; ls2[t] = s2;
    __syncthreads();
    for (int st = 128; st > 0; st >>= 1) {
        if (t < st) { ls[t] += ls[t + st]; ls2[t] += ls2[t + st]; }
        __syncthreads();
    }
    if (t == 0) {
        float mean = ls[0] * (1.f / 4096.f);
        float var = ls2[0] * (1.f / 4096.f) - mean * mean;
        float rstd = rsqrtf(var + 1e-5f);
        float sc = g1_l[o] * rstd;
        bnsc[o] = sc;
        bnsh[o] = beta1_l[o] - mean * sc;
    }
}

// ---------------- conv W2 with fused BN+ReLU on A, desc update epilogue ----------------
__global__ __launch_bounds__(256) void conv2_kernel(
    const float* __restrict__ out1, const unsigned short* __restrict__ W2_l,
    const float* __restrict__ b2_l, const float* __restrict__ bnsc,
    const float* __restrict__ bnsh, float* __restrict__ desc,
    unsigned short* __restrict__ xbf) {
    __shared__ float ssc[512], ssh[512];
    for (int i = threadIdx.x; i < 512; i += 256) { ssc[i] = bnsc[i]; ssh[i] = bnsh[i]; }
    __syncthreads();
    int bb = blockIdx.z;
    const float* A = out1 + (size_t)bb * NN * 512;
    int n0 = blockIdx.x * 128, o0 = blockIdx.y * 64;
    int w = threadIdx.x >> 6, lane = threadIdx.x & 63, quad = lane >> 4, l15 = lane & 15;
    int wrow = (w & 1) * 64, wcol = (w >> 1) * 32;
    f32x4 acc[4][2];
#pragma unroll
    for (int r = 0; r < 4; r++)
#pragma unroll
        for (int c = 0; c < 2; c++) acc[r][c] = (f32x4){0.f, 0.f, 0.f, 0.f};
    for (int kk = 0; kk < 512; kk += 32) {
        bf16x8 bf[2], af[4];
#pragma unroll
        for (int cs = 0; cs < 2; cs++)
            bf[cs] = *(const bf16x8*)(W2_l + (size_t)(o0 + wcol + cs * 16 + l15) * 512 + kk + quad * 8);
#pragma unroll
        for (int rs = 0; rs < 4; rs++) {
            const float* ap = A + (size_t)(n0 + wrow + rs * 16 + l15) * 512 + kk + quad * 8;
            f32x4 v0 = *(const f32x4*)ap;
            f32x4 v1 = *(const f32x4*)(ap + 4);
            union { bf16x8 v; unsigned short u[8]; } pk;
            int kbase = kk + quad * 8;
#pragma unroll
            for (int j = 0; j < 4; j++)
                pk.u[j] = f2bf(fmaxf(0.f, v0[j] * ssc[kbase + j] + ssh[kbase + j]));
#pragma unroll
            for (int j = 0; j < 4; j++)
                pk.u[4 + j] = f2bf(fmaxf(0.f, v1[j] * ssc[kbase + 4 + j] + ssh[kbase + 4 + j]));
            af[rs] = pk.v;
        }
#pragma unroll
        for (int rs = 0; rs < 4; rs++)
#pragma unroll
            for (int cs = 0; cs < 2; cs++)
                acc[rs][cs] = mfma16(af[rs], bf[cs], acc[rs][cs]);
    }
#pragma unroll
    for (int rs = 0; rs < 4; rs++)
#pragma unroll
        for (int cs = 0; cs < 2; cs++)
#pragma unroll
            for (int reg = 0; reg < 4; reg++) {
                int n = n0 + wrow + rs * 16 + quad * 4 + reg;
                int o = o0 + wcol + cs * 16 + l15;
                size_t di = ((size_t)bb * NN + n) * DD + o;
                float nd = desc[di] + acc[rs][cs][reg] + b2_l[o];
                desc[di] = nd;
                xbf[di] = f2bf(nd);
            }
}

extern "C" void kernel_launch(void* const* d_in, const int* in_sizes, int n_in,
                              void* d_out, int out_size, void* d_ws, size_t ws_size,
                              hipStream_t stream) {
    const float* desc0 = (const float*)d_in[0];
    const float* desc1 = (const float*)d_in[1];
    const float* M0p   = (const float*)d_in[2];
    const float* M1p   = (const float*)d_in[3];
    const float* Wq = (const float*)d_in[4];  const float* bq = (const float*)d_in[5];
    const float* Wk = (const float*)d_in[6];  const float* bk = (const float*)d_in[7];
    const float* Wv = (const float*)d_in[8];  const float* bv = (const float*)d_in[9];
    const float* Wm = (const float*)d_in[10]; const float* bm = (const float*)d_in[11];
    const float* W1 = (const float*)d_in[12]; const float* b1 = (const float*)d_in[13];
    const float* g1 = (const float*)d_in[14]; const float* beta1 = (const float*)d_in[15];
    const float* W2 = (const float*)d_in[16]; const float* b2 = (const float*)d_in[17];
    float* out = (float*)d_out;
    char* ws = (char*)d_ws;

    float*          desc  = (float*)(ws);                              // 4 MB
    unsigned short* xbf   = (unsigned short*)(ws + (4ull << 20));      // 2 MB
    unsigned short* qb    = (unsigned short*)(ws + (6ull << 20));      // 2 MB
    unsigned short* kbuf  = (unsigned short*)(ws + (8ull << 20));      // 2 MB
    unsigned short* vbuf  = (unsigned short*)(ws + (10ull << 20));     // 2 MB
    unsigned short* xattn = (unsigned short*)(ws + (12ull << 20));     // 2 MB
    unsigned short* ymsg  = (unsigned short*)(ws + (14ull << 20));     // 2 MB
    float*          out1  = (float*)(ws + (16ull << 20));              // 8 MB
    float*          bnsc  = (float*)(ws + (24ull << 20));              // 2 KB
    float*          bnsh  = bnsc + 512;                                // 2 KB
    unsigned short* wbf   = (unsigned short*)(ws + (24ull << 20) + 4096); // ~7.9 MB

    const int SQ = LL * 65536;

    wconv_kernel<<<15360, 256, 0, stream>>>(Wq, Wk, Wv, Wm, W1, W2, wbf);
    init_kernel<<<4096, 256, 0, stream>>>(desc0, desc1, desc, xbf);

    for (int l = 0; l < LL; l++) {
        int cross = l & 1;
        const unsigned short* Wq_l = wbf + (size_t)l * 65536;
        const unsigned short* Wk_l = wbf + SQ + (size_t)l * 65536;
        const unsigned short* Wv_l = wbf + 2 * (size_t)SQ + (size_t)l * 65536;
        const unsigned short* Wm_l = wbf + 3 * (size_t)SQ + (size_t)l * 65536;
        const unsigned short* W1_l = wbf + 4 * (size_t)SQ + (size_t)l * 262144;
        const unsigned short* W2_l = wbf + 4 * (size_t)SQ + (size_t)LL * 262144 + (size_t)l * 131072;

        proj_kernel<<<dim3(8, 4, 12), 256, 0, stream>>>(
            xbf, Wq_l, Wk_l, Wv_l, bq + l * 256, bk + l * 256, bv + l * 256,
            qb, kbuf, vbuf, cross);
        flash_kernel<<<dim3(16, 16), 256, 0, stream>>>(qb, kbuf, vbuf, M0p, M1p, xattn);
        merge_kernel<<<dim3(8, 4, 4), 256, 0, stream>>>(xattn, Wm_l, bm + l * 256, ymsg);
        conv1_kernel<<<dim3(8, 8, 4), 256, 0, stream>>>(xbf, ymsg, W1_l, b1 + l * 512, out1);
        bnstats_kernel<<<512, 256, 0, stream>>>(out1, g1 + l * 512, beta1 + l * 512, bnsc, bnsh);
        conv2_kernel<<<dim3(8, 4, 4), 256, 0, stream>>>(out1, W2_l, b2 + l * 256, bnsc, bnsh, desc, xbf);
    }

    final_kernel<<<4096, 256, 0, stream>>>(desc, out);
}

// Round 2
// 801.184 us; speedup vs baseline: 1.1573x; 1.1573x over previous
//
#include <hip/hip_runtime.h>
#include <hip/hip_bf16.h>

#define NN 1024
#define DD 256
#define LL 6

typedef __attribute__((ext_vector_type(8))) short bf16x8;
typedef __attribute__((ext_vector_type(4))) float f32x4;

__device__ __forceinline__ unsigned short f2bf(float f) {
    union { float f; unsigned u; } x; x.f = f;
    return (unsigned short)((x.u + 0x7fffu + ((x.u >> 16) & 1u)) >> 16);
}

__device__ __forceinline__ f32x4 mfma16(bf16x8 a, bf16x8 b, f32x4 c) {
    return __builtin_amdgcn_mfma_f32_16x16x32_bf16(a, b, c, 0, 0, 0);
}

// ---------------- weight fp32 -> bf16 conversion ----------------
__global__ void wconv_kernel(const float* __restrict__ Wq, const float* __restrict__ Wk,
                             const float* __restrict__ Wv, const float* __restrict__ Wm,
                             const float* __restrict__ W1, const float* __restrict__ W2,
                             unsigned short* __restrict__ dst) {
    const int SQ = LL * 65536;
    const int S1 = LL * 262144;
    int idx = blockIdx.x * 256 + threadIdx.x;
    int total = 4 * SQ + S1 + LL * 131072;
    if (idx >= total) return;
    float v;
    if (idx < 4 * SQ) {
        int seg = idx / SQ, off = idx % SQ;
        const float* p = (seg == 0) ? Wq : (seg == 1) ? Wk : (seg == 2) ? Wv : Wm;
        v = p[off];
    } else if (idx < 4 * SQ + S1) {
        v = W1[idx - 4 * SQ];
    } else {
        v = W2[idx - 4 * SQ - S1];
    }
    dst[idx] = f2bf(v);
}

// ---------------- init: transpose [2][256][1024] -> [4][1024][256] ----------------
__global__ void init_kernel(const float* __restrict__ desc0, const float* __restrict__ desc1,
                            float* __restrict__ desc, unsigned short* __restrict__ xbf) {
    int idx = blockIdx.x * 256 + threadIdx.x;
    int c = idx & 255, n = (idx >> 8) & 1023, bb = idx >> 18;
    const float* src = (bb < 2) ? (desc0 + ((size_t)bb * DD + c) * NN + n)
                                : (desc1 + ((size_t)(bb - 2) * DD + c) * NN + n);
    float v = *src;
    desc[idx] = v;
    xbf[idx] = f2bf(v);
}

// ---------------- final: transpose [4][1024][256] -> [4][256][1024] ----------------
__global__ void final_kernel(const float* __restrict__ desc, float* __restrict__ out) {
    int idx = blockIdx.x * 256 + threadIdx.x;
    int n = idx & 1023, c = (idx >> 10) & 255, bb = idx >> 18;
    out[idx] = desc[((size_t)bb * NN + n) * DD + c];
}

// ---------------- q/k/v projections ----------------
__global__ __launch_bounds__(256) void proj_kernel(
    const unsigned short* __restrict__ xbf,
    const unsigned short* __restrict__ Wq_l, const unsigned short* __restrict__ Wk_l,
    const unsigned short* __restrict__ Wv_l,
    const float* __restrict__ bq_l, const float* __restrict__ bk_l,
    const float* __restrict__ bv_l,
    unsigned short* __restrict__ qb, unsigned short* __restrict__ kb,
    unsigned short* __restrict__ vb, int cross) {
    int z = blockIdx.z;
    int bb = z / 3, mat = z % 3;
    int srcbb = (mat == 0) ? bb : (cross ? (bb ^ 2) : bb);
    const unsigned short* A = xbf + (size_t)srcbb * NN * DD;
    const unsigned short* W = (mat == 0) ? Wq_l : (mat == 1) ? Wk_l : Wv_l;
    const float* bias = (mat == 0) ? bq_l : (mat == 1) ? bk_l : bv_l;
    int n0 = blockIdx.x * 128, o0 = blockIdx.y * 64;
    int w = threadIdx.x >> 6, lane = threadIdx.x & 63, quad = lane >> 4, l15 = lane & 15;
    int wrow = (w & 1) * 64, wcol = (w >> 1) * 32;
    f32x4 acc[4][2];
#pragma unroll
    for (int r = 0; r < 4; r++)
#pragma unroll
        for (int c = 0; c < 2; c++) acc[r][c] = (f32x4){0.f, 0.f, 0.f, 0.f};
    for (int kk = 0; kk < DD; kk += 32) {
        bf16x8 bf[2], af[4];
#pragma unroll
        for (int cs = 0; cs < 2; cs++)
            bf[cs] = *(const bf16x8*)(W + (size_t)(o0 + wcol + cs * 16 + l15) * DD + kk + quad * 8);
#pragma unroll
        for (int rs = 0; rs < 4; rs++)
            af[rs] = *(const bf16x8*)(A + (size_t)(n0 + wrow + rs * 16 + l15) * DD + kk + quad * 8);
#pragma unroll
        for (int rs = 0; rs < 4; rs++)
#pragma unroll
            for (int cs = 0; cs < 2; cs++)
                acc[rs][cs] = mfma16(af[rs], bf[cs], acc[rs][cs]);
    }
#pragma unroll
    for (int rs = 0; rs < 4; rs++)
#pragma unroll
        for (int cs = 0; cs < 2; cs++)
#pragma unroll
            for (int reg = 0; reg < 4; reg++) {
                int n = n0 + wrow + rs * 16 + quad * 4 + reg;
                int o = o0 + wcol + cs * 16 + l15;
                float val = acc[rs][cs][reg] + bias[o];
                int h = o & 3, d = o >> 2;
                if (mat < 2) {
                    unsigned short* dst = (mat == 0) ? qb : kb;
                    dst[((size_t)(bb * 4 + h) * NN + n) * 64 + d] = f2bf(val);
                } else {
                    vb[((size_t)(bb * 4 + h) * 64 + d) * NN + n] = f2bf(val);
                }
            }
}

// ---------------- flash attention per (b,h): no barriers, SW-pipelined ----------------
__global__ __launch_bounds__(256) void flash_kernel(
    const unsigned short* __restrict__ qb, const unsigned short* __restrict__ kb,
    const unsigned short* __restrict__ vb,
    const float* __restrict__ M0, const float* __restrict__ M1,
    unsigned short* __restrict__ xattn) {
    int bh = blockIdx.y;
    int bb = bh >> 2, h = bh & 3;
    int nb = blockIdx.x;
    int w = threadIdx.x >> 6, lane = threadIdx.x & 63, quad = lane >> 4, l15 = lane & 15;
    const float* mask = (bb < 2) ? (M0 + (size_t)bb * NN * NN) : (M1 + (size_t)(bb - 2) * NN * NN);
    const unsigned short* Q = qb + (size_t)bh * NN * 64;
    const unsigned short* Kb = kb + (size_t)bh * NN * 64;
    const unsigned short* Vb = vb + (size_t)bh * 64 * NN;
    int row0 = nb * 64 + w * 16;

    bf16x8 qf[2];
#pragma unroll
    for (int kc = 0; kc < 2; kc++)
        qf[kc] = *(const bf16x8*)(Q + (size_t)(row0 + l15) * 64 + kc * 32 + quad * 8);

    // per-wave private P tile (no cross-wave deps -> NO barriers)
    __shared__ __align__(16) unsigned short Plds[4][16][72];

    const float* mrow[4];
#pragma unroll
    for (int reg = 0; reg < 4; reg++)
        mrow[reg] = mask + (size_t)(row0 + quad * 4 + reg) * NN;

    f32x4 Oa[4];
#pragma unroll
    for (int dt = 0; dt < 4; dt++) Oa[dt] = (f32x4){0.f, 0.f, 0.f, 0.f};
    float mrun[4], lrun[4];
#pragma unroll
    for (int r = 0; r < 4; r++) { mrun[r] = -1e30f; lrun[r] = 0.f; }

    // prologue: load K-frags and mask values for tile 0
    bf16x8 kf[8];
    float mv[4][4];
#pragma unroll
    for (int t = 0; t < 4; t++)
#pragma unroll
        for (int kc = 0; kc < 2; kc++)
            kf[t * 2 + kc] = *(const bf16x8*)(Kb + (size_t)(t * 16 + l15) * 64 + kc * 32 + quad * 8);
#pragma unroll
    for (int t = 0; t < 4; t++)
#pragma unroll
        for (int reg = 0; reg < 4; reg++)
            mv[t][reg] = mrow[reg][t * 16 + l15];

    for (int mt = 0; mt < 16; mt++) {
        int m0 = mt * 64;
        // QK^T MFMAs with current K-frags
        f32x4 s[4];
#pragma unroll
        for (int t = 0; t < 4; t++) s[t] = (f32x4){0.f, 0.f, 0.f, 0.f};
#pragma unroll
        for (int t = 0; t < 4; t++)
#pragma unroll
            for (int kc = 0; kc < 2; kc++)
                s[t] = mfma16(qf[kc], kf[t * 2 + kc], s[t]);

        // V loads for current tile (independent of softmax -> overlap)
        bf16x8 vf[8];
#pragma unroll
        for (int dt = 0; dt < 4; dt++)
#pragma unroll
            for (int kc = 0; kc < 2; kc++)
                vf[dt * 2 + kc] = *(const bf16x8*)(Vb + (size_t)(dt * 16 + l15) * NN + m0 + kc * 32 + quad * 8);

        // prefetch next tile's K-frags and mask (hidden behind softmax VALU)
        bf16x8 kf2[8];
        float mv2[4][4];
        if (mt < 15) {
            int m1 = m0 + 64;
#pragma unroll
            for (int t = 0; t < 4; t++)
#pragma unroll
                for (int kc = 0; kc < 2; kc++)
                    kf2[t * 2 + kc] = *(const bf16x8*)(Kb + (size_t)(m1 + t * 16 + l15) * 64 + kc * 32 + quad * 8);
#pragma unroll
            for (int t = 0; t < 4; t++)
#pragma unroll
                for (int reg = 0; reg < 4; reg++)
                    mv2[t][reg] = mrow[reg][m1 + t * 16 + l15];
        }

        // softmax (online)
        float sv[4][4], rmax[4];
#pragma unroll
        for (int r = 0; r < 4; r++) rmax[r] = -1e30f;
#pragma unroll
        for (int t = 0; t < 4; t++)
#pragma unroll
            for (int reg = 0; reg < 4; reg++) {
                float v = s[t][reg] * 0.125f * mv[t][reg];
                sv[t][reg] = v;
                rmax[reg] = fmaxf(rmax[reg], v);
            }
#pragma unroll
        for (int reg = 0; reg < 4; reg++) {
            rmax[reg] = fmaxf(rmax[reg], __shfl_xor(rmax[reg], 1, 64));
            rmax[reg] = fmaxf(rmax[reg], __shfl_xor(rmax[reg], 2, 64));
            rmax[reg] = fmaxf(rmax[reg], __shfl_xor(rmax[reg], 4, 64));
            rmax[reg] = fmaxf(rmax[reg], __shfl_xor(rmax[reg], 8, 64));
        }
        float alpha[4], rsum[4];
#pragma unroll
        for (int reg = 0; reg < 4; reg++) {
            float mn = fmaxf(mrun[reg], rmax[reg]);
            alpha[reg] = __expf(mrun[reg] - mn);
            mrun[reg] = mn;
            rsum[reg] = 0.f;
        }
#pragma unroll
        for (int t = 0; t < 4; t++)
#pragma unroll
            for (int reg = 0; reg < 4; reg++) {
                float p = __expf(sv[t][reg] - mrun[reg]);
                sv[t][reg] = p;
                rsum[reg] += p;
            }
#pragma unroll
        for (int reg = 0; reg < 4; reg++) {
            rsum[reg] += __shfl_xor(rsum[reg], 1, 64);
            rsum[reg] += __shfl_xor(rsum[reg], 2, 64);
            rsum[reg] += __shfl_xor(rsum[reg], 4, 64);
            rsum[reg] += __shfl_xor(rsum[reg], 8, 64);
            lrun[reg] = lrun[reg] * alpha[reg] + rsum[reg];
        }
#pragma unroll
        for (int dt = 0; dt < 4; dt++)
#pragma unroll
            for (int reg = 0; reg < 4; reg++) Oa[dt][reg] *= alpha[reg];

        // P: C-layout -> A-layout via per-wave LDS (no barrier needed)
#pragma unroll
        for (int t = 0; t < 4; t++)
#pragma unroll
            for (int reg = 0; reg < 4; reg++)
                Plds[w][quad * 4 + reg][t * 16 + l15] = f2bf(sv[t][reg]);
        bf16x8 pf[2];
#pragma unroll
        for (int kc = 0; kc < 2; kc++)
            pf[kc] = *(const bf16x8*)(&Plds[w][l15][kc * 32 + quad * 8]);
#pragma unroll
        for (int dt = 0; dt < 4; dt++)
#pragma unroll
            for (int kc = 0; kc < 2; kc++)
                Oa[dt] = mfma16(pf[kc], vf[dt * 2 + kc], Oa[dt]);

        if (mt < 15) {
#pragma unroll
            for (int i = 0; i < 8; i++) kf[i] = kf2[i];
#pragma unroll
            for (int t = 0; t < 4; t++)
#pragma unroll
                for (int reg = 0; reg < 4; reg++) mv[t][reg] = mv2[t][reg];
        }
    }
#pragma unroll
    for (int dt = 0; dt < 4; dt++)
#pragma unroll
        for (int reg = 0; reg < 4; reg++) {
            int n = row0 + quad * 4 + reg;
            int d = dt * 16 + l15;
            float val = Oa[dt][reg] / lrun[reg];
            xattn[((size_t)bb * NN + n) * DD + d * 4 + h] = f2bf(val);
        }
}

// ---------------- merge conv ----------------
__global__ __launch_bounds__(256) void merge_kernel(
    const unsigned short* __restrict__ xattn, const unsigned short* __restrict__ Wm_l,
    const float* __restrict__ bm_l, unsigned short* __restrict__ ymsg) {
    int bb = blockIdx.z;
    const unsigned short* A = xattn + (size_t)bb * NN * DD;
    int n0 = blockIdx.x * 128, o0 = blockIdx.y * 64;
    int w = threadIdx.x >> 6, lane = threadIdx.x & 63, quad = lane >> 4, l15 = lane & 15;
    int wrow = (w & 1) * 64, wcol = (w >> 1) * 32;
    f32x4 acc[4][2];
#pragma unroll
    for (int r = 0; r < 4; r++)
#pragma unroll
        for (int c = 0; c < 2; c++) acc[r][c] = (f32x4){0.f, 0.f, 0.f, 0.f};
    for (int kk = 0; kk < DD; kk += 32) {
        bf16x8 bf[2], af[4];
#pragma unroll
        for (int cs = 0; cs < 2; cs++)
            bf[cs] = *(const bf16x8*)(Wm_l + (size_t)(o0 + wcol + cs * 16 + l15) * DD + kk + quad * 8);
#pragma unroll
        for (int rs = 0; rs < 4; rs++)
            af[rs] = *(const bf16x8*)(A + (size_t)(n0 + wrow + rs * 16 + l15) * DD + kk + quad * 8);
#pragma unroll
        for (int rs = 0; rs < 4; rs++)
#pragma unroll
            for (int cs = 0; cs < 2; cs++)
                acc[rs][cs] = mfma16(af[rs], bf[cs], acc[rs][cs]);
    }
#pragma unroll
    for (int rs = 0; rs < 4; rs++)
#pragma unroll
        for (int cs = 0; cs < 2; cs++)
#pragma unroll
            for (int reg = 0; reg < 4; reg++) {
                int n = n0 + wrow + rs * 16 + quad * 4 + reg;
                int o = o0 + wcol + cs * 16 + l15;
                ymsg[((size_t)bb * NN + n) * DD + o] = f2bf(acc[rs][cs][reg] + bm_l[o]);
            }
}

// ---------------- conv W1 (concat[x,msg] as split-K A) ----------------
__global__ __launch_bounds__(256) void conv1_kernel(
    const unsigned short* __restrict__ xbf, const unsigned short* __restrict__ ymsg,
    const unsigned short* __restrict__ W1_l, const float* __restrict__ b1_l,
    float* __restrict__ out1) {
    int bb = blockIdx.z;
    const unsigned short* A1 = xbf + (size_t)bb * NN * DD;
    const unsigned short* A2 = ymsg + (size_t)bb * NN * DD;
    int n0 = blockIdx.x * 128, o0 = blockIdx.y * 64;
    int w = threadIdx.x >> 6, lane = threadIdx.x & 63, quad = lane >> 4, l15 = lane & 15;
    int wrow = (w & 1) * 64, wcol = (w >> 1) * 32;
    f32x4 acc[4][2];
#pragma unroll
    for (int r = 0; r < 4; r++)
#pragma unroll
        for (int c = 0; c < 2; c++) acc[r][c] = (f32x4){0.f, 0.f, 0.f, 0.f};
    for (int kk = 0; kk < 512; kk += 32) {
        const unsigned short* As = (kk < 256) ? A1 : A2;
        int kl = kk & 255;
        bf16x8 bf[2], af[4];
#pragma unroll
        for (int cs = 0; cs < 2; cs++)
            bf[cs] = *(const bf16x8*)(W1_l + (size_t)(o0 + wcol + cs * 16 + l15) * 512 + kk + quad * 8);
#pragma unroll
        for (int rs = 0; rs < 4; rs++)
            af[rs] = *(const bf16x8*)(As + (size_t)(n0 + wrow + rs * 16 + l15) * DD + kl + quad * 8);
#pragma unroll
        for (int rs = 0; rs < 4; rs++)
#pragma unroll
            for (int cs = 0; cs < 2; cs++)
                acc[rs][cs] = mfma16(af[rs], bf[cs], acc[rs][cs]);
    }
#pragma unroll
    for (int rs = 0; rs < 4; rs++)
#pragma unroll
        for (int cs = 0; cs < 2; cs++)
#pragma unroll
            for (int reg = 0; reg < 4; reg++) {
                int n = n0 + wrow + rs * 16 + quad * 4 + reg;
                int o = o0 + wcol + cs * 16 + l15;
                out1[((size_t)bb * NN + n) * 512 + o] = acc[rs][cs][reg] + b1_l[o];
            }
}

// ---------------- BN stats stage 1: coalesced partial sums ----------------
// grid 32 blocks; block b covers rows [b*128, b*128+128); thread t owns channels t, t+256
__global__ __launch_bounds__(256) void bnpart_kernel(
    const float* __restrict__ out1, float* __restrict__ bnpart) {
    int b = blockIdx.x, t = threadIdx.x;
    const float* base = out1 + (size_t)b * 128 * 512;
    float s0 = 0.f, s20 = 0.f, s1 = 0.f, s21 = 0.f;
    for (int r = 0; r < 128; r++) {
        float v0 = base[(size_t)r * 512 + t];
        float v1 = base[(size_t)r * 512 + t + 256];
        s0 += v0; s20 += v0 * v0;
        s1 += v1; s21 += v1 * v1;
    }
    float* p = bnpart + ((size_t)b * 512) * 2;
    p[t * 2 + 0] = s0; p[t * 2 + 1] = s20;
    p[(t + 256) * 2 + 0] = s1; p[(t + 256) * 2 + 1] = s21;
}

// ---------------- BN stats stage 2: finalize scale/shift ----------------
__global__ __launch_bounds__(256) void bnfinal_kernel(
    const float* __restrict__ bnpart, const float* __restrict__ g1_l,
    const float* __restrict__ beta1_l, float* __restrict__ bnsc, float* __restrict__ bnsh) {
    int o = blockIdx.x * 256 + threadIdx.x;   // 0..511
    float s = 0.f, s2 = 0.f;
    for (int b = 0; b < 32; b++) {
        s += bnpart[((size_t)b * 512 + o) * 2 + 0];
        s2 += bnpart[((size_t)b * 512 + o) * 2 + 1];
    }
    float mean = s * (1.f / 4096.f);
    float var = s2 * (1.f / 4096.f) - mean * mean;
    float rstd = rsqrtf(var + 1e-5f);
    float sc = g1_l[o] * rstd;
    bnsc[o] = sc;
    bnsh[o] = beta1_l[o] - mean * sc;
}

// ---------------- conv W2 with fused BN+ReLU on A, desc update epilogue ----------------
__global__ __launch_bounds__(256) void conv2_kernel(
    const float* __restrict__ out1, const unsigned short* __restrict__ W2_l,
    const float* __restrict__ b2_l, const float* __restrict__ bnsc,
    const float* __restrict__ bnsh, float* __restrict__ desc,
    unsigned short* __restrict__ xbf) {
    __shared__ float ssc[512], ssh[512];
    for (int i = threadIdx.x; i < 512; i += 256) { ssc[i] = bnsc[i]; ssh[i] = bnsh[i]; }
    __syncthreads();
    int bb = blockIdx.z;
    const float* A = out1 + (size_t)bb * NN * 512;
    int n0 = blockIdx.x * 128, o0 = blockIdx.y * 64;
    int w = threadIdx.x >> 6, lane = threadIdx.x & 63, quad = lane >> 4, l15 = lane & 15;
    int wrow = (w & 1) * 64, wcol = (w >> 1) * 32;
    f32x4 acc[4][2];
#pragma unroll
    for (int r = 0; r < 4; r++)
#pragma unroll
        for (int c = 0; c < 2; c++) acc[r][c] = (f32x4){0.f, 0.f, 0.f, 0.f};
    for (int kk = 0; kk < 512; kk += 32) {
        bf16x8 bf[2], af[4];
#pragma unroll
        for (int cs = 0; cs < 2; cs++)
            bf[cs] = *(const bf16x8*)(W2_l + (size_t)(o0 + wcol + cs * 16 + l15) * 512 + kk + quad * 8);
#pragma unroll
        for (int rs = 0; rs < 4; rs++) {
            const float* ap = A + (size_t)(n0 + wrow + rs * 16 + l15) * 512 + kk + quad * 8;
            f32x4 v0 = *(const f32x4*)ap;
            f32x4 v1 = *(const f32x4*)(ap + 4);
            union { bf16x8 v; unsigned short u[8]; } pk;
            int kbase = kk + quad * 8;
#pragma unroll
            for (int j = 0; j < 4; j++)
                pk.u[j] = f2bf(fmaxf(0.f, v0[j] * ssc[kbase + j] + ssh[kbase + j]));
#pragma unroll
            for (int j = 0; j < 4; j++)
                pk.u[4 + j] = f2bf(fmaxf(0.f, v1[j] * ssc[kbase + 4 + j] + ssh[kbase + 4 + j]));
            af[rs] = pk.v;
        }
#pragma unroll
        for (int rs = 0; rs < 4; rs++)
#pragma unroll
            for (int cs = 0; cs < 2; cs++)
                acc[rs][cs] = mfma16(af[rs], bf[cs], acc[rs][cs]);
    }
#pragma unroll
    for (int rs = 0; rs < 4; rs++)
#pragma unroll
        for (int cs = 0; cs < 2; cs++)
#pragma unroll
            for (int reg = 0; reg < 4; reg++) {
                int n = n0 + wrow + rs * 16 + quad * 4 + reg;
                int o = o0 + wcol + cs * 16 + l15;
                size_t di = ((size_t)bb * NN + n) * DD + o;
                float nd = desc[di] + acc[rs][cs][reg] + b2_l[o];
                desc[di] = nd;
                xbf[di] = f2bf(nd);
            }
}

extern "C" void kernel_launch(void* const* d_in, const int* in_sizes, int n_in,
                              void* d_out, int out_size, void* d_ws, size_t ws_size,
                              hipStream_t stream) {
    const float* desc0 = (const float*)d_in[0];
    const float* desc1 = (const float*)d_in[1];
    const float* M0p   = (const float*)d_in[2];
    const float* M1p   = (const float*)d_in[3];
    const float* Wq = (const float*)d_in[4];  const float* bq = (const float*)d_in[5];
    const float* Wk = (const float*)d_in[6];  const float* bk = (const float*)d_in[7];
    const float* Wv = (const float*)d_in[8];  const float* bv = (const float*)d_in[9];
    const float* Wm = (const float*)d_in[10]; const float* bm = (const float*)d_in[11];
    const float* W1 = (const float*)d_in[12]; const float* b1 = (const float*)d_in[13];
    const float* g1 = (const float*)d_in[14]; const float* beta1 = (const float*)d_in[15];
    const float* W2 = (const float*)d_in[16]; const float* b2 = (const float*)d_in[17];
    float* out = (float*)d_out;
    char* ws = (char*)d_ws;

    float*          desc  = (float*)(ws);                              // 4 MB
    unsigned short* xbf   = (unsigned short*)(ws + (4ull << 20));      // 2 MB
    unsigned short* qb    = (unsigned short*)(ws + (6ull << 20));      // 2 MB
    unsigned short* kbuf  = (unsigned short*)(ws + (8ull << 20));      // 2 MB
    unsigned short* vbuf  = (unsigned short*)(ws + (10ull << 20));     // 2 MB
    unsigned short* xattn = (unsigned short*)(ws + (12ull << 20));     // 2 MB
    unsigned short* ymsg  = (unsigned short*)(ws + (14ull << 20));     // 2 MB
    float*          out1  = (float*)(ws + (16ull << 20));              // 8 MB
    float*          bnsc  = (float*)(ws + (24ull << 20));              // 2 KB
    float*          bnsh  = bnsc + 512;                                // 2 KB
    unsigned short* wbf   = (unsigned short*)(ws + (24ull << 20) + 4096); // ~7.5 MB
    float*          bnpart= (float*)(ws + (32ull << 20));              // 128 KB

    const int SQ = LL * 65536;

    wconv_kernel<<<15360, 256, 0, stream>>>(Wq, Wk, Wv, Wm, W1, W2, wbf);
    init_kernel<<<4096, 256, 0, stream>>>(desc0, desc1, desc, xbf);

    for (int l = 0; l < LL; l++) {
        int cross = l & 1;
        const unsigned short* Wq_l = wbf + (size_t)l * 65536;
        const unsigned short* Wk_l = wbf + SQ + (size_t)l * 65536;
        const unsigned short* Wv_l = wbf + 2 * (size_t)SQ + (size_t)l * 65536;
        const unsigned short* Wm_l = wbf + 3 * (size_t)SQ + (size_t)l * 65536;
        const unsigned short* W1_l = wbf + 4 * (size_t)SQ + (size_t)l * 262144;
        const unsigned short* W2_l = wbf + 4 * (size_t)SQ + (size_t)LL * 262144 + (size_t)l * 131072;

        proj_kernel<<<dim3(8, 4, 12), 256, 0, stream>>>(
            xbf, Wq_l, Wk_l, Wv_l, bq + l * 256, bk + l * 256, bv + l * 256,
            qb, kbuf, vbuf, cross);
        flash_kernel<<<dim3(16, 16), 256, 0, stream>>>(qb, kbuf, vbuf, M0p, M1p, xattn);
        merge_kernel<<<dim3(8, 4, 4), 256, 0, stream>>>(xattn, Wm_l, bm + l * 256, ymsg);
        conv1_kernel<<<dim3(8, 8, 4), 256, 0, stream>>>(xbf, ymsg, W1_l, b1 + l * 512, out1);
        bnpart_kernel<<<32, 256, 0, stream>>>(out1, bnpart);
        bnfinal_kernel<<<2, 256, 0, stream>>>(bnpart, g1 + l * 512, beta1 + l * 512, bnsc, bnsh);
        conv2_kernel<<<dim3(8, 4, 4), 256, 0, stream>>>(out1, W2_l, b2 + l * 256, bnsc, bnsh, desc, xbf);
    }

    final_kernel<<<4096, 256, 0, stream>>>(desc, out);
}

// Round 3
// 697.002 us; speedup vs baseline: 1.3303x; 1.1495x over previous
//
#include <hip/hip_runtime.h>
#include <hip/hip_bf16.h>

#define NN 1024
#define DD 256
#define LL 6

typedef __attribute__((ext_vector_type(8))) short bf16x8;
typedef __attribute__((ext_vector_type(4))) float f32x4;

__device__ __forceinline__ unsigned short f2bf(float f) {
    union { float f; unsigned u; } x; x.f = f;
    return (unsigned short)((x.u + 0x7fffu + ((x.u >> 16) & 1u)) >> 16);
}

__device__ __forceinline__ float bf2f(unsigned short u) {
    union { unsigned u; float f; } x; x.u = ((unsigned)u) << 16; return x.f;
}

__device__ __forceinline__ f32x4 mfma16(bf16x8 a, bf16x8 b, f32x4 c) {
    return __builtin_amdgcn_mfma_f32_16x16x32_bf16(a, b, c, 0, 0, 0);
}

// ---------------- weight fp32 -> bf16 conversion ----------------
__global__ void wconv_kernel(const float* __restrict__ Wq, const float* __restrict__ Wk,
                             const float* __restrict__ Wv, const float* __restrict__ Wm,
                             const float* __restrict__ W1, const float* __restrict__ W2,
                             unsigned short* __restrict__ dst) {
    const int SQ = LL * 65536;
    const int S1 = LL * 262144;
    int idx = blockIdx.x * 256 + threadIdx.x;
    int total = 4 * SQ + S1 + LL * 131072;
    if (idx >= total) return;
    float v;
    if (idx < 4 * SQ) {
        int seg = idx / SQ, off = idx % SQ;
        const float* p = (seg == 0) ? Wq : (seg == 1) ? Wk : (seg == 2) ? Wv : Wm;
        v = p[off];
    } else if (idx < 4 * SQ + S1) {
        v = W1[idx - 4 * SQ];
    } else {
        v = W2[idx - 4 * SQ - S1];
    }
    dst[idx] = f2bf(v);
}

// ---------------- fold: W1m_perm[l][o][h*64+d] = sum_j W1[l][o][256+j] * Wm[l][j][d*4+h]
__global__ __launch_bounds__(256) void fold1_kernel(const float* __restrict__ W1,
                                                    const float* __restrict__ Wm,
                                                    unsigned short* __restrict__ W1m) {
    int l = blockIdx.y;
    int o0 = blockIdx.x * 16;
    int i = threadIdx.x;
    const float* W1b = W1 + (size_t)l * 512 * 512;
    const float* Wmb = Wm + (size_t)l * 65536;
    float acc[16];
#pragma unroll
    for (int t = 0; t < 16; t++) acc[t] = 0.f;
    for (int j = 0; j < 256; j++) {
        float wm = Wmb[(size_t)j * 256 + i];
#pragma unroll
        for (int t = 0; t < 16; t++)
            acc[t] += W1b[(size_t)(o0 + t) * 512 + 256 + j] * wm;
    }
    int pc = (i & 3) * 64 + (i >> 2);   // (d,h) -> h*64+d with i = d*4+h
#pragma unroll
    for (int t = 0; t < 16; t++)
        W1m[((size_t)l * 512 + o0 + t) * 256 + pc] = f2bf(acc[t]);
}

// ---------------- fold: bmix[l][o] = b1[l][o] + sum_j W1[l][o][256+j]*bm[l][j]
__global__ void fold2_kernel(const float* __restrict__ W1, const float* __restrict__ bm,
                             const float* __restrict__ b1, float* __restrict__ bmix) {
    int idx = blockIdx.x * 256 + threadIdx.x;   // 3072
    int l = idx >> 9, o = idx & 511;
    const float* row = W1 + ((size_t)l * 512 + o) * 512 + 256;
    const float* bmr = bm + (size_t)l * 256;
    float acc = 0.f;
    for (int j = 0; j < 256; j++) acc += row[j] * bmr[j];
    bmix[idx] = b1[idx] + acc;
}

// ---------------- init: transpose [2][256][1024] -> [4][1024][256] ----------------
__global__ void init_kernel(const float* __restrict__ desc0, const float* __restrict__ desc1,
                            float* __restrict__ desc, unsigned short* __restrict__ xbf) {
    int idx = blockIdx.x * 256 + threadIdx.x;
    int c = idx & 255, n = (idx >> 8) & 1023, bb = idx >> 18;
    const float* src = (bb < 2) ? (desc0 + ((size_t)bb * DD + c) * NN + n)
                                : (desc1 + ((size_t)(bb - 2) * DD + c) * NN + n);
    float v = *src;
    desc[idx] = v;
    xbf[idx] = f2bf(v);
}

// ---------------- final: transpose [4][1024][256] -> [4][256][1024] ----------------
__global__ void final_kernel(const float* __restrict__ desc, float* __restrict__ out) {
    int idx = blockIdx.x * 256 + threadIdx.x;
    int n = idx & 1023, c = (idx >> 10) & 255, bb = idx >> 18;
    out[idx] = desc[((size_t)bb * NN + n) * DD + c];
}

// ---------------- q/k/v projections: 64x64 tile, pipelined K ----------------
__global__ __launch_bounds__(256) void proj_kernel(
    const unsigned short* __restrict__ xbf,
    const unsigned short* __restrict__ Wq_l, const unsigned short* __restrict__ Wk_l,
    const unsigned short* __restrict__ Wv_l,
    const float* __restrict__ bq_l, const float* __restrict__ bk_l,
    const float* __restrict__ bv_l,
    unsigned short* __restrict__ qb, unsigned short* __restrict__ kb,
    unsigned short* __restrict__ vb, int cross) {
    int z = blockIdx.z;
    int bb = z / 3, mat = z % 3;
    int srcbb = (mat == 0) ? bb : (cross ? (bb ^ 2) : bb);
    const unsigned short* A = xbf + (size_t)srcbb * NN * DD;
    const unsigned short* W = (mat == 0) ? Wq_l : (mat == 1) ? Wk_l : Wv_l;
    const float* bias = (mat == 0) ? bq_l : (mat == 1) ? bk_l : bv_l;
    int n0 = blockIdx.x * 64, o0 = blockIdx.y * 64;
    int w = threadIdx.x >> 6, lane = threadIdx.x & 63, quad = lane >> 4, l15 = lane & 15;
    int wr = (w & 1) * 32, wc = (w >> 1) * 32;
    const unsigned short* Ab = A + (size_t)(n0 + wr + l15) * DD + quad * 8;
    const unsigned short* Wb = W + (size_t)(o0 + wc + l15) * DD + quad * 8;
    f32x4 acc[2][2];
#pragma unroll
    for (int r = 0; r < 2; r++)
#pragma unroll
        for (int c = 0; c < 2; c++) acc[r][c] = (f32x4){0.f, 0.f, 0.f, 0.f};
    bf16x8 a0, a1, b0, b1, a0n, a1n, b0n, b1n;
    a0 = *(const bf16x8*)(Ab);
    a1 = *(const bf16x8*)(Ab + 16 * DD);
    b0 = *(const bf16x8*)(Wb);
    b1 = *(const bf16x8*)(Wb + 16 * DD);
#pragma unroll
    for (int s = 0; s < 8; s++) {
        if (s < 7) {
            int kk = (s + 1) * 32;
            a0n = *(const bf16x8*)(Ab + kk);
            a1n = *(const bf16x8*)(Ab + 16 * DD + kk);
            b0n = *(const bf16x8*)(Wb + kk);
            b1n = *(const bf16x8*)(Wb + 16 * DD + kk);
        }
        acc[0][0] = mfma16(a0, b0, acc[0][0]);
        acc[0][1] = mfma16(a0, b1, acc[0][1]);
        acc[1][0] = mfma16(a1, b0, acc[1][0]);
        acc[1][1] = mfma16(a1, b1, acc[1][1]);
        if (s < 7) { a0 = a0n; a1 = a1n; b0 = b0n; b1 = b1n; }
    }
    float qscale = (mat == 0) ? 0.125f : 1.0f;   // fold 1/sqrt(64) into q
#pragma unroll
    for (int rs = 0; rs < 2; rs++)
#pragma unroll
        for (int cs = 0; cs < 2; cs++)
#pragma unroll
            for (int reg = 0; reg < 4; reg++) {
                int n = n0 + wr + rs * 16 + quad * 4 + reg;
                int o = o0 + wc + cs * 16 + l15;
                float val = (acc[rs][cs][reg] + bias[o]) * qscale;
                int h = o & 3, d = o >> 2;
                if (mat < 2) {
                    unsigned short* dst = (mat == 0) ? qb : kb;
                    dst[((size_t)(bb * 4 + h) * NN + n) * 64 + d] = f2bf(val);
                } else {
                    vb[((size_t)(bb * 4 + h) * 64 + d) * NN + n] = f2bf(val);
                }
            }
}

// ---------------- flash attention: 8 waves, 2-way m-split, LDS merge ----------------
__global__ __launch_bounds__(512, 4) void flash_kernel(
    const unsigned short* __restrict__ qb, const unsigned short* __restrict__ kb,
    const unsigned short* __restrict__ vb,
    const float* __restrict__ M0, const float* __restrict__ M1,
    unsigned short* __restrict__ xattn, float* __restrict__ bnsumm) {
    __shared__ __align__(16) char smem[51200];
    unsigned short* Plds = (unsigned short*)smem;   // phase 1: [8][16][88]
    float* OL = (float*)smem;                        // phase 2: [8][64][25]

    int bh = blockIdx.y, nb = blockIdx.x;
    int bb = bh >> 2, h = bh & 3;
    int tid = threadIdx.x, w = tid >> 6, lane = tid & 63, quad = lane >> 4, l15 = lane & 15;
    int qg = w & 3, sp = w >> 2;

    if (nb == 0 && bh == 0) { bnsumm[tid] = 0.f; bnsumm[tid + 512] = 0.f; }

    const float* mask = (bb < 2) ? (M0 + (size_t)bb * NN * NN) : (M1 + (size_t)(bb - 2) * NN * NN);
    const unsigned short* Q = qb + (size_t)bh * NN * 64;
    const unsigned short* Kb = kb + (size_t)bh * NN * 64;
    const unsigned short* Vb = vb + (size_t)bh * 64 * NN;
    int row0 = nb * 64 + qg * 16;

    bf16x8 qf[2];
#pragma unroll
    for (int kc = 0; kc < 2; kc++)
        qf[kc] = *(const bf16x8*)(Q + (size_t)(row0 + l15) * 64 + kc * 32 + quad * 8);

    const float* mrow[4];
#pragma unroll
    for (int reg = 0; reg < 4; reg++)
        mrow[reg] = mask + (size_t)(row0 + quad * 4 + reg) * NN;

    f32x4 Oa[4];
#pragma unroll
    for (int dt = 0; dt < 4; dt++) Oa[dt] = (f32x4){0.f, 0.f, 0.f, 0.f};
    float mrun[4], lrun[4];
#pragma unroll
    for (int r = 0; r < 4; r++) { mrun[r] = -1e30f; lrun[r] = 0.f; }

    unsigned short* Pw = Plds + w * (16 * 88);

    for (int mt = 0; mt < 8; mt++) {
        int m0 = sp * 512 + mt * 64;
        f32x4 s4[4];
#pragma unroll
        for (int t = 0; t < 4; t++) s4[t] = (f32x4){0.f, 0.f, 0.f, 0.f};
#pragma unroll
        for (int t = 0; t < 4; t++)
#pragma unroll
            for (int kc = 0; kc < 2; kc++) {
                bf16x8 kf = *(const bf16x8*)(Kb + (size_t)(m0 + t * 16 + l15) * 64 + kc * 32 + quad * 8);
                s4[t] = mfma16(qf[kc], kf, s4[t]);
            }
        bf16x8 vf[8];
#pragma unroll
        for (int dt = 0; dt < 4; dt++)
#pragma unroll
            for (int kc = 0; kc < 2; kc++)
                vf[dt * 2 + kc] = *(const bf16x8*)(Vb + (size_t)(dt * 16 + l15) * NN + m0 + kc * 32 + quad * 8);
        float mv[4][4];
#pragma unroll
        for (int t = 0; t < 4; t++)
#pragma unroll
            for (int reg = 0; reg < 4; reg++)
                mv[t][reg] = mrow[reg][m0 + t * 16 + l15];

        float sv[4][4], rmax[4];
#pragma unroll
        for (int r = 0; r < 4; r++) rmax[r] = -1e30f;
#pragma unroll
        for (int t = 0; t < 4; t++)
#pragma unroll
            for (int reg = 0; reg < 4; reg++) {
                float v = s4[t][reg] * mv[t][reg];   // q already scaled
                sv[t][reg] = v;
                rmax[reg] = fmaxf(rmax[reg], v);
            }
#pragma unroll
        for (int reg = 0; reg < 4; reg++) {
            rmax[reg] = fmaxf(rmax[reg], __shfl_xor(rmax[reg], 1, 64));
            rmax[reg] = fmaxf(rmax[reg], __shfl_xor(rmax[reg], 2, 64));
            rmax[reg] = fmaxf(rmax[reg], __shfl_xor(rmax[reg], 4, 64));
            rmax[reg] = fmaxf(rmax[reg], __shfl_xor(rmax[reg], 8, 64));
        }
        float alpha[4], rsum[4];
#pragma unroll
        for (int reg = 0; reg < 4; reg++) {
            float mn = fmaxf(mrun[reg], rmax[reg]);
            alpha[reg] = __expf(mrun[reg] - mn);
            mrun[reg] = mn;
            rsum[reg] = 0.f;
        }
#pragma unroll
        for (int t = 0; t < 4; t++)
#pragma unroll
            for (int reg = 0; reg < 4; reg++) {
                float p = __expf(sv[t][reg] - mrun[reg]);
                sv[t][reg] = p;
                rsum[reg] += p;
            }
#pragma unroll
        for (int reg = 0; reg < 4; reg++) {
            rsum[reg] += __shfl_xor(rsum[reg], 1, 64);
            rsum[reg] += __shfl_xor(rsum[reg], 2, 64);
            rsum[reg] += __shfl_xor(rsum[reg], 4, 64);
            rsum[reg] += __shfl_xor(rsum[reg], 8, 64);
            lrun[reg] = lrun[reg] * alpha[reg] + rsum[reg];
        }
#pragma unroll
        for (int dt = 0; dt < 4; dt++)
#pragma unroll
            for (int reg = 0; reg < 4; reg++) Oa[dt][reg] *= alpha[reg];
#pragma unroll
        for (int t = 0; t < 4; t++)
#pragma unroll
            for (int reg = 0; reg < 4; reg++)
                Pw[(quad * 4 + reg) * 88 + t * 16 + l15] = f2bf(sv[t][reg]);
        bf16x8 pf[2];
#pragma unroll
        for (int kc = 0; kc < 2; kc++)
            pf[kc] = *(const bf16x8*)(Pw + l15 * 88 + kc * 32 + quad * 8);
#pragma unroll
        for (int dt = 0; dt < 4; dt++)
#pragma unroll
            for (int kc = 0; kc < 2; kc++)
                Oa[dt] = mfma16(pf[kc], vf[dt * 2 + kc], Oa[dt]);
    }
    __syncthreads();   // phase change: Plds -> OL
    float* mine = OL + (size_t)(w * 64 + lane) * 25;
#pragma unroll
    for (int dt = 0; dt < 4; dt++)
#pragma unroll
        for (int reg = 0; reg < 4; reg++) mine[dt * 4 + reg] = Oa[dt][reg];
#pragma unroll
    for (int reg = 0; reg < 4; reg++) { mine[16 + reg] = mrun[reg]; mine[20 + reg] = lrun[reg]; }
    __syncthreads();
    if (sp == 0) {
        const float* p0 = OL + (size_t)(w * 64 + lane) * 25;
        const float* p1 = OL + (size_t)((w + 4) * 64 + lane) * 25;
        float e0[4], e1[4], li[4];
#pragma unroll
        for (int reg = 0; reg < 4; reg++) {
            float m0v = p0[16 + reg], m1v = p1[16 + reg];
            float M = fmaxf(m0v, m1v);
            e0[reg] = __expf(m0v - M);
            e1[reg] = __expf(m1v - M);
            li[reg] = 1.f / (p0[20 + reg] * e0[reg] + p1[20 + reg] * e1[reg]);
        }
#pragma unroll
        for (int dt = 0; dt < 4; dt++)
#pragma unroll
            for (int reg = 0; reg < 4; reg++) {
                float val = (p0[dt * 4 + reg] * e0[reg] + p1[dt * 4 + reg] * e1[reg]) * li[reg];
                int n = row0 + quad * 4 + reg;
                int col = h * 64 + dt * 16 + l15;   // [h*64+d] layout, matches W1m_perm
                xattn[((size_t)bb * NN + n) * DD + col] = f2bf(val);
            }
    }
}

// ---------------- conv1 = W1[:, :256]*x + W1m*attn + bmix, fused BN stats ----------------
__global__ __launch_bounds__(256) void conv1_kernel(
    const unsigned short* __restrict__ xbf, const unsigned short* __restrict__ xattn,
    const unsigned short* __restrict__ W1_l, const unsigned short* __restrict__ W1m_l,
    const float* __restrict__ bmix_l,
    unsigned short* __restrict__ out1, float* __restrict__ bnsumm) {
    int bb = blockIdx.z;
    int n0 = blockIdx.x * 64, o0 = blockIdx.y * 64;
    int w = threadIdx.x >> 6, lane = threadIdx.x & 63, quad = lane >> 4, l15 = lane & 15;
    int wr = (w & 1) * 32, wc = (w >> 1) * 32;
    const unsigned short* A1 = xbf + (size_t)bb * NN * DD + (size_t)(n0 + wr + l15) * DD + quad * 8;
    const unsigned short* A2 = xattn + (size_t)bb * NN * DD + (size_t)(n0 + wr + l15) * DD + quad * 8;
    const unsigned short* Wa = W1_l + (size_t)(o0 + wc + l15) * 512 + quad * 8;
    const unsigned short* Wb = W1m_l + (size_t)(o0 + wc + l15) * DD + quad * 8;
    f32x4 acc[2][2];
#pragma unroll
    for (int r = 0; r < 2; r++)
#pragma unroll
        for (int c = 0; c < 2; c++) acc[r][c] = (f32x4){0.f, 0.f, 0.f, 0.f};

    auto ldA = [&](int s, int rs) -> bf16x8 {
        return (s < 8) ? *(const bf16x8*)(A1 + rs * 16 * DD + s * 32)
                       : *(const bf16x8*)(A2 + rs * 16 * DD + (s - 8) * 32);
    };
    auto ldB = [&](int s, int cs) -> bf16x8 {
        return (s < 8) ? *(const bf16x8*)(Wa + cs * 16 * 512 + s * 32)
                       : *(const bf16x8*)(Wb + cs * 16 * DD + (s - 8) * 32);
    };
    bf16x8 a0 = ldA(0, 0), a1 = ldA(0, 1), b0 = ldB(0, 0), b1 = ldB(0, 1);
    bf16x8 a0n, a1n, b0n, b1n;
#pragma unroll
    for (int s = 0; s < 16; s++) {
        if (s < 15) { a0n = ldA(s + 1, 0); a1n = ldA(s + 1, 1); b0n = ldB(s + 1, 0); b1n = ldB(s + 1, 1); }
        acc[0][0] = mfma16(a0, b0, acc[0][0]);
        acc[0][1] = mfma16(a0, b1, acc[0][1]);
        acc[1][0] = mfma16(a1, b0, acc[1][0]);
        acc[1][1] = mfma16(a1, b1, acc[1][1]);
        if (s < 15) { a0 = a0n; a1 = a1n; b0 = b0n; b1 = b1n; }
    }
    __shared__ float redS[4][32], redQ[4][32];
    float cs_s[2] = {0.f, 0.f}, cs_q[2] = {0.f, 0.f};
#pragma unroll
    for (int rs = 0; rs < 2; rs++)
#pragma unroll
        for (int cs = 0; cs < 2; cs++)
#pragma unroll
            for (int reg = 0; reg < 4; reg++) {
                int n = n0 + wr + rs * 16 + quad * 4 + reg;
                int o = o0 + wc + cs * 16 + l15;
                float val = acc[rs][cs][reg] + bmix_l[o];
                out1[((size_t)bb * NN + n) * 512 + o] = f2bf(val);
                cs_s[cs] += val;
                cs_q[cs] += val * val;
            }
#pragma unroll
    for (int cs = 0; cs < 2; cs++) {
        cs_s[cs] += __shfl_down(cs_s[cs], 32, 64);
        cs_s[cs] += __shfl_down(cs_s[cs], 16, 64);
        cs_q[cs] += __shfl_down(cs_q[cs], 32, 64);
        cs_q[cs] += __shfl_down(cs_q[cs], 16, 64);
    }
    if (lane < 16) {
#pragma unroll
        for (int cs = 0; cs < 2; cs++) {
            redS[w][cs * 16 + l15] = cs_s[cs];
            redQ[w][cs * 16 + l15] = cs_q[cs];
        }
    }
    __syncthreads();
    if (threadIdx.x < 64) {
        int c = threadIdx.x;
        int p = (c < 32) ? 0 : 2;
        int ci = c & 31;
        atomicAdd(&bnsumm[o0 + c], redS[p][ci] + redS[p + 1][ci]);
        atomicAdd(&bnsumm[512 + o0 + c], redQ[p][ci] + redQ[p + 1][ci]);
    }
}

// ---------------- BN finalize ----------------
__global__ void bnfinal_kernel(const float* __restrict__ bnsumm, const float* __restrict__ g1_l,
                               const float* __restrict__ beta1_l,
                               float* __restrict__ bnsc, float* __restrict__ bnsh) {
    int o = blockIdx.x * 256 + threadIdx.x;
    float s = bnsumm[o], s2 = bnsumm[512 + o];
    float mean = s * (1.f / 4096.f);
    float var = s2 * (1.f / 4096.f) - mean * mean;
    float sc = g1_l[o] * rsqrtf(var + 1e-5f);
    bnsc[o] = sc;
    bnsh[o] = beta1_l[o] - mean * sc;
}

// ---------------- BN apply + ReLU -> bf16 ----------------
__global__ __launch_bounds__(256) void bnrelu_kernel(
    const unsigned short* __restrict__ out1, const float* __restrict__ bnsc,
    const float* __restrict__ bnsh, unsigned short* __restrict__ ybf) {
    int idx = blockIdx.x * 256 + threadIdx.x;
    int base = idx * 8;
    int o = base & 511;
    union { bf16x8 v; unsigned short u[8]; } in, outp;
    in.v = *(const bf16x8*)(out1 + base);
    f32x4 sc0 = *(const f32x4*)(bnsc + o), sc1 = *(const f32x4*)(bnsc + o + 4);
    f32x4 sh0 = *(const f32x4*)(bnsh + o), sh1 = *(const f32x4*)(bnsh + o + 4);
#pragma unroll
    for (int j = 0; j < 4; j++)
        outp.u[j] = f2bf(fmaxf(0.f, bf2f(in.u[j]) * sc0[j] + sh0[j]));
#pragma unroll
    for (int j = 0; j < 4; j++)
        outp.u[4 + j] = f2bf(fmaxf(0.f, bf2f(in.u[4 + j]) * sc1[j] + sh1[j]));
    *(bf16x8*)(ybf + base) = outp.v;
}

// ---------------- conv2: 32x64 tile, pipelined, residual epilogue ----------------
__global__ __launch_bounds__(256) void conv2_kernel(
    const unsigned short* __restrict__ ybf, const unsigned short* __restrict__ W2_l,
    const float* __restrict__ b2_l, float* __restrict__ desc,
    unsigned short* __restrict__ xbf) {
    int bb = blockIdx.z;
    int n0 = blockIdx.x * 32, o0 = blockIdx.y * 64;
    int w = threadIdx.x >> 6, lane = threadIdx.x & 63, quad = lane >> 4, l15 = lane & 15;
    int wr = (w & 1) * 16, wc = (w >> 1) * 32;
    const unsigned short* Ab = ybf + ((size_t)bb * NN + n0 + wr + l15) * 512 + quad * 8;
    const unsigned short* Wb = W2_l + (size_t)(o0 + wc + l15) * 512 + quad * 8;
    f32x4 acc[2];
    acc[0] = (f32x4){0.f, 0.f, 0.f, 0.f};
    acc[1] = (f32x4){0.f, 0.f, 0.f, 0.f};
    bf16x8 a0 = *(const bf16x8*)(Ab);
    bf16x8 b0 = *(const bf16x8*)(Wb);
    bf16x8 b1 = *(const bf16x8*)(Wb + 16 * 512);
    bf16x8 a0n, b0n, b1n;
#pragma unroll
    for (int s = 0; s < 16; s++) {
        if (s < 15) {
            int kk = (s + 1) * 32;
            a0n = *(const bf16x8*)(Ab + kk);
            b0n = *(const bf16x8*)(Wb + kk);
            b1n = *(const bf16x8*)(Wb + 16 * 512 + kk);
        }
        acc[0] = mfma16(a0, b0, acc[0]);
        acc[1] = mfma16(a0, b1, acc[1]);
        if (s < 15) { a0 = a0n; b0 = b0n; b1 = b1n; }
    }
#pragma unroll
    for (int cs = 0; cs < 2; cs++)
#pragma unroll
        for (int reg = 0; reg < 4; reg++) {
            int n = n0 + wr + quad * 4 + reg;
            int o = o0 + wc + cs * 16 + l15;
            size_t di = ((size_t)bb * NN + n) * DD + o;
            float nd = desc[di] + acc[cs][reg] + b2_l[o];
            desc[di] = nd;
            xbf[di] = f2bf(nd);
        }
}

extern "C" void kernel_launch(void* const* d_in, const int* in_sizes, int n_in,
                              void* d_out, int out_size, void* d_ws, size_t ws_size,
                              hipStream_t stream) {
    const float* desc0 = (const float*)d_in[0];
    const float* desc1 = (const float*)d_in[1];
    const float* M0p   = (const float*)d_in[2];
    const float* M1p   = (const float*)d_in[3];
    const float* Wq = (const float*)d_in[4];  const float* bq = (const float*)d_in[5];
    const float* Wk = (const float*)d_in[6];  const float* bk = (const float*)d_in[7];
    const float* Wv = (const float*)d_in[8];  const float* bv = (const float*)d_in[9];
    const float* Wm = (const float*)d_in[10]; const float* bm = (const float*)d_in[11];
    const float* W1 = (const float*)d_in[12]; const float* b1 = (const float*)d_in[13];
    const float* g1 = (const float*)d_in[14]; const float* beta1 = (const float*)d_in[15];
    const float* W2 = (const float*)d_in[16]; const float* b2 = (const float*)d_in[17];
    float* out = (float*)d_out;
    char* ws = (char*)d_ws;

    float*          desc   = (float*)(ws);                               // 4 MB
    unsigned short* xbf    = (unsigned short*)(ws + (4ull << 20));       // 2 MB
    unsigned short* qb     = (unsigned short*)(ws + (6ull << 20));       // 2 MB
    unsigned short* kbuf   = (unsigned short*)(ws + (8ull << 20));       // 2 MB
    unsigned short* vbuf   = (unsigned short*)(ws + (10ull << 20));      // 2 MB
    unsigned short* xattn  = (unsigned short*)(ws + (12ull << 20));      // 2 MB
    unsigned short* out1   = (unsigned short*)(ws + (14ull << 20));      // 4 MB (bf16)
    unsigned short* ybf    = (unsigned short*)(ws + (18ull << 20));      // 4 MB (bf16)
    float*          bnsumm = (float*)(ws + (22ull << 20));               // 4 KB (sum | sumsq)
    float*          bnsc   = (float*)(ws + (22ull << 20) + 8192);        // 2 KB
    float*          bnsh   = (float*)(ws + (22ull << 20) + 12288);       // 2 KB
    float*          bmix   = (float*)(ws + (22ull << 20) + 16384);       // 12 KB
    unsigned short* W1m    = (unsigned short*)(ws + (23ull << 20));      // 1.5 MB
    unsigned short* wbf    = (unsigned short*)(ws + (25ull << 20));      // 7.5 MB

    const int SQ = LL * 65536;

    wconv_kernel<<<15360, 256, 0, stream>>>(Wq, Wk, Wv, Wm, W1, W2, wbf);
    init_kernel<<<4096, 256, 0, stream>>>(desc0, desc1, desc, xbf);
    fold1_kernel<<<dim3(32, 6), 256, 0, stream>>>(W1, Wm, W1m);
    fold2_kernel<<<12, 256, 0, stream>>>(W1, bm, b1, bmix);

    for (int l = 0; l < LL; l++) {
        int cross = l & 1;
        const unsigned short* Wq_l = wbf + (size_t)l * 65536;
        const unsigned short* Wk_l = wbf + SQ + (size_t)l * 65536;
        const unsigned short* Wv_l = wbf + 2 * (size_t)SQ + (size_t)l * 65536;
        const unsigned short* W1_l = wbf + 4 * (size_t)SQ + (size_t)l * 262144;
        const unsigned short* W2_l = wbf + 4 * (size_t)SQ + (size_t)LL * 262144 + (size_t)l * 131072;
        const unsigned short* W1m_l = W1m + (size_t)l * 131072;

        proj_kernel<<<dim3(16, 4, 12), 256, 0, stream>>>(
            xbf, Wq_l, Wk_l, Wv_l, bq + l * 256, bk + l * 256, bv + l * 256,
            qb, kbuf, vbuf, cross);
        flash_kernel<<<dim3(16, 16), 512, 0, stream>>>(qb, kbuf, vbuf, M0p, M1p, xattn, bnsumm);
        conv1_kernel<<<dim3(16, 8, 4), 256, 0, stream>>>(
            xbf, xattn, W1_l, W1m_l, bmix + l * 512, out1, bnsumm);
        bnfinal_kernel<<<2, 256, 0, stream>>>(bnsumm, g1 + l * 512, beta1 + l * 512, bnsc, bnsh);
        bnrelu_kernel<<<1024, 256, 0, stream>>>(out1, bnsc, bnsh, ybf);
        conv2_kernel<<<dim3(32, 4, 4), 256, 0, stream>>>(ybf, W2_l, b2 + l * 256, desc, xbf);
    }

    final_kernel<<<4096, 256, 0, stream>>>(desc, out);
}

// Round 4
// 632.356 us; speedup vs baseline: 1.4663x; 1.1022x over previous
//
#include <hip/hip_runtime.h>
#include <hip/hip_bf16.h>

#define NN 1024
#define DD 256
#define LL 6

typedef __attribute__((ext_vector_type(8))) short bf16x8;
typedef __attribute__((ext_vector_type(4))) float f32x4;
typedef __attribute__((ext_vector_type(4))) unsigned short u16x4;

__device__ __forceinline__ unsigned short f2bf(float f) {
    union { float f; unsigned u; } x; x.f = f;
    return (unsigned short)((x.u + 0x7fffu + ((x.u >> 16) & 1u)) >> 16);
}

__device__ __forceinline__ float bf2f(unsigned short u) {
    union { unsigned u; float f; } x; x.u = ((unsigned)u) << 16; return x.f;
}

__device__ __forceinline__ f32x4 mfma16(bf16x8 a, bf16x8 b, f32x4 c) {
    return __builtin_amdgcn_mfma_f32_16x16x32_bf16(a, b, c, 0, 0, 0);
}

// ---------------- weight fp32 -> bf16 conversion ----------------
__global__ void wconv_kernel(const float* __restrict__ Wq, const float* __restrict__ Wk,
                             const float* __restrict__ Wv, const float* __restrict__ Wm,
                             const float* __restrict__ W1, const float* __restrict__ W2,
                             unsigned short* __restrict__ dst) {
    const int SQ = LL * 65536;
    const int S1 = LL * 262144;
    int idx = blockIdx.x * 256 + threadIdx.x;
    int total = 4 * SQ + S1 + LL * 131072;
    if (idx >= total) return;
    float v;
    if (idx < 4 * SQ) {
        int seg = idx / SQ, off = idx % SQ;
        const float* p = (seg == 0) ? Wq : (seg == 1) ? Wk : (seg == 2) ? Wv : Wm;
        v = p[off];
    } else if (idx < 4 * SQ + S1) {
        v = W1[idx - 4 * SQ];
    } else {
        v = W2[idx - 4 * SQ - S1];
    }
    dst[idx] = f2bf(v);
}

// ---------------- mask fp32 -> bf16 ----------------
__global__ void maskconv_kernel(const float* __restrict__ M0, const float* __restrict__ M1,
                                unsigned short* __restrict__ mbf) {
    int idx = blockIdx.x * 256 + threadIdx.x;     // 1M threads, 4 elems each
    size_t base = (size_t)idx * 4;
    int bb = (int)(base >> 20);
    const float* src = (bb < 2) ? (M0 + base) : (M1 + base - (2ull << 20));
    f32x4 v = *(const f32x4*)src;
    u16x4 o;
#pragma unroll
    for (int j = 0; j < 4; j++) o[j] = f2bf(v[j]);
    *(u16x4*)(mbf + base) = o;
}

// ---------------- fold1 (MFMA): W1m_perm[l][o][h*64+d] = sum_j W1[l][o][256+j]*Wm[l][j][d*4+h]
__global__ __launch_bounds__(256) void fold1_kernel(const unsigned short* __restrict__ W1bf,
                                                    const unsigned short* __restrict__ Wmbf,
                                                    unsigned short* __restrict__ W1m) {
    int l = blockIdx.z;
    int o0 = blockIdx.x * 64, i0 = blockIdx.y * 64;
    const unsigned short* A = W1bf + (size_t)l * 262144;   // [512][512]
    const unsigned short* B = Wmbf + (size_t)l * 65536;    // [256][256]
    __shared__ unsigned short Bt[64][264];                  // [i][k] transposed
    int t = threadIdx.x;
#pragma unroll
    for (int r = 0; r < 8; r++) {
        int j = r * 32 + (t >> 3);
        int il = (t & 7) * 8;
        union { bf16x8 v; unsigned short u[8]; } ld;
        ld.v = *(const bf16x8*)(B + (size_t)j * 256 + i0 + il);
#pragma unroll
        for (int jj = 0; jj < 8; jj++) Bt[il + jj][j] = ld.u[jj];
    }
    __syncthreads();
    int w = t >> 6, lane = t & 63, quad = lane >> 4, l15 = lane & 15;
    int wr = (w & 1) * 32, wc = (w >> 1) * 32;
    const unsigned short* Ab = A + (size_t)(o0 + wr + l15) * 512 + 256 + quad * 8;
    f32x4 acc[2][2];
#pragma unroll
    for (int r = 0; r < 2; r++)
#pragma unroll
        for (int c = 0; c < 2; c++) acc[r][c] = (f32x4){0.f, 0.f, 0.f, 0.f};
#pragma unroll
    for (int s = 0; s < 8; s++) {
        int kk = s * 32;
        bf16x8 a0 = *(const bf16x8*)(Ab + kk);
        bf16x8 a1 = *(const bf16x8*)(Ab + 16 * 512 + kk);
        bf16x8 b0 = *(const bf16x8*)(&Bt[wc + l15][kk + quad * 8]);
        bf16x8 b1 = *(const bf16x8*)(&Bt[wc + 16 + l15][kk + quad * 8]);
        acc[0][0] = mfma16(a0, b0, acc[0][0]);
        acc[0][1] = mfma16(a0, b1, acc[0][1]);
        acc[1][0] = mfma16(a1, b0, acc[1][0]);
        acc[1][1] = mfma16(a1, b1, acc[1][1]);
    }
#pragma unroll
    for (int rs = 0; rs < 2; rs++)
#pragma unroll
        for (int cs = 0; cs < 2; cs++)
#pragma unroll
            for (int reg = 0; reg < 4; reg++) {
                int o = o0 + wr + rs * 16 + quad * 4 + reg;
                int i = i0 + wc + cs * 16 + l15;
                int pc = (i & 3) * 64 + (i >> 2);
                W1m[((size_t)l * 512 + o) * 256 + pc] = f2bf(acc[rs][cs][reg]);
            }
}

// ---------------- fold2: bmix[l][o] = b1 + dot(W1[l][o][256:], bm[l]) — one wave/output
__global__ __launch_bounds__(256) void fold2_kernel(const float* __restrict__ W1,
                                                    const float* __restrict__ bm,
                                                    const float* __restrict__ b1,
                                                    float* __restrict__ bmix) {
    int wid = blockIdx.x * 4 + (threadIdx.x >> 6);   // 0..3071
    int lane = threadIdx.x & 63;
    int l = wid >> 9, o = wid & 511;
    const float* row = W1 + ((size_t)l * 512 + o) * 512 + 256;
    const float* bmr = bm + (size_t)l * 256;
    f32x4 r = *(const f32x4*)(row + lane * 4);
    f32x4 bb4 = *(const f32x4*)(bmr + lane * 4);
    float acc = r[0] * bb4[0] + r[1] * bb4[1] + r[2] * bb4[2] + r[3] * bb4[3];
    acc += __shfl_xor(acc, 1, 64);
    acc += __shfl_xor(acc, 2, 64);
    acc += __shfl_xor(acc, 4, 64);
    acc += __shfl_xor(acc, 8, 64);
    acc += __shfl_xor(acc, 16, 64);
    acc += __shfl_xor(acc, 32, 64);
    if (lane == 0) bmix[wid] = b1[wid] + acc;
}

// ---------------- init: transpose [2][256][1024] -> [4][1024][256] ----------------
__global__ void init_kernel(const float* __restrict__ desc0, const float* __restrict__ desc1,
                            float* __restrict__ desc, unsigned short* __restrict__ xbf) {
    int idx = blockIdx.x * 256 + threadIdx.x;
    int c = idx & 255, n = (idx >> 8) & 1023, bb = idx >> 18;
    const float* src = (bb < 2) ? (desc0 + ((size_t)bb * DD + c) * NN + n)
                                : (desc1 + ((size_t)(bb - 2) * DD + c) * NN + n);
    float v = *src;
    desc[idx] = v;
    xbf[idx] = f2bf(v);
}

// ---------------- final: transpose [4][1024][256] -> [4][256][1024] ----------------
__global__ void final_kernel(const float* __restrict__ desc, float* __restrict__ out) {
    int idx = blockIdx.x * 256 + threadIdx.x;
    int n = idx & 1023, c = (idx >> 10) & 255, bb = idx >> 18;
    out[idx] = desc[((size_t)bb * NN + n) * DD + c];
}

// ---------------- q/k/v projections: 64x64 tile, pipelined K ----------------
__global__ __launch_bounds__(256) void proj_kernel(
    const unsigned short* __restrict__ xbf,
    const unsigned short* __restrict__ Wq_l, const unsigned short* __restrict__ Wk_l,
    const unsigned short* __restrict__ Wv_l,
    const float* __restrict__ bq_l, const float* __restrict__ bk_l,
    const float* __restrict__ bv_l,
    unsigned short* __restrict__ qb, unsigned short* __restrict__ kb,
    unsigned short* __restrict__ vb, int cross) {
    int z = blockIdx.z;
    int bb = z / 3, mat = z % 3;
    int srcbb = (mat == 0) ? bb : (cross ? (bb ^ 2) : bb);
    const unsigned short* A = xbf + (size_t)srcbb * NN * DD;
    const unsigned short* W = (mat == 0) ? Wq_l : (mat == 1) ? Wk_l : Wv_l;
    const float* bias = (mat == 0) ? bq_l : (mat == 1) ? bk_l : bv_l;
    int n0 = blockIdx.x * 64, o0 = blockIdx.y * 64;
    int w = threadIdx.x >> 6, lane = threadIdx.x & 63, quad = lane >> 4, l15 = lane & 15;
    int wr = (w & 1) * 32, wc = (w >> 1) * 32;
    const unsigned short* Ab = A + (size_t)(n0 + wr + l15) * DD + quad * 8;
    const unsigned short* Wb = W + (size_t)(o0 + wc + l15) * DD + quad * 8;
    f32x4 acc[2][2];
#pragma unroll
    for (int r = 0; r < 2; r++)
#pragma unroll
        for (int c = 0; c < 2; c++) acc[r][c] = (f32x4){0.f, 0.f, 0.f, 0.f};
    bf16x8 a0, a1, b0, b1, a0n, a1n, b0n, b1n;
    a0 = *(const bf16x8*)(Ab);
    a1 = *(const bf16x8*)(Ab + 16 * DD);
    b0 = *(const bf16x8*)(Wb);
    b1 = *(const bf16x8*)(Wb + 16 * DD);
#pragma unroll
    for (int s = 0; s < 8; s++) {
        if (s < 7) {
            int kk = (s + 1) * 32;
            a0n = *(const bf16x8*)(Ab + kk);
            a1n = *(const bf16x8*)(Ab + 16 * DD + kk);
            b0n = *(const bf16x8*)(Wb + kk);
            b1n = *(const bf16x8*)(Wb + 16 * DD + kk);
        }
        acc[0][0] = mfma16(a0, b0, acc[0][0]);
        acc[0][1] = mfma16(a0, b1, acc[0][1]);
        acc[1][0] = mfma16(a1, b0, acc[1][0]);
        acc[1][1] = mfma16(a1, b1, acc[1][1]);
        if (s < 7) { a0 = a0n; a1 = a1n; b0 = b0n; b1 = b1n; }
    }
    float qscale = (mat == 0) ? 0.125f : 1.0f;   // fold 1/sqrt(64) into q
#pragma unroll
    for (int rs = 0; rs < 2; rs++)
#pragma unroll
        for (int cs = 0; cs < 2; cs++)
#pragma unroll
            for (int reg = 0; reg < 4; reg++) {
                int n = n0 + wr + rs * 16 + quad * 4 + reg;
                int o = o0 + wc + cs * 16 + l15;
                float val = (acc[rs][cs][reg] + bias[o]) * qscale;
                int h = o & 3, d = o >> 2;
                if (mat < 2) {
                    unsigned short* dst = (mat == 0) ? qb : kb;
                    dst[((size_t)(bb * 4 + h) * NN + n) * 64 + d] = f2bf(val);
                } else {
                    vb[((size_t)(bb * 4 + h) * 64 + d) * NN + n] = f2bf(val);
                }
            }
}

// ---------------- flash attention: 8 waves, 2-way m-split, LDS merge ----------------
__global__ __launch_bounds__(512, 4) void flash_kernel(
    const unsigned short* __restrict__ qb, const unsigned short* __restrict__ kb,
    const unsigned short* __restrict__ vb,
    const unsigned short* __restrict__ maskbf,
    unsigned short* __restrict__ xattn, float* __restrict__ bnsumm) {
    __shared__ __align__(16) char smem[51200];
    unsigned short* Plds = (unsigned short*)smem;   // phase 1: [8][16][88]
    float* OL = (float*)smem;                        // phase 2: [8][64][25]

    int bh = blockIdx.y, nb = blockIdx.x;
    int bb = bh >> 2, h = bh & 3;
    int tid = threadIdx.x, w = tid >> 6, lane = tid & 63, quad = lane >> 4, l15 = lane & 15;
    int qg = w & 3, sp = w >> 2;

    if (nb == 0 && bh == 0) { bnsumm[tid] = 0.f; bnsumm[tid + 512] = 0.f; }

    const unsigned short* mask = maskbf + (size_t)bb * NN * NN;
    const unsigned short* Q = qb + (size_t)bh * NN * 64;
    const unsigned short* Kb = kb + (size_t)bh * NN * 64;
    const unsigned short* Vb = vb + (size_t)bh * 64 * NN;
    int row0 = nb * 64 + qg * 16;

    bf16x8 qf[2];
#pragma unroll
    for (int kc = 0; kc < 2; kc++)
        qf[kc] = *(const bf16x8*)(Q + (size_t)(row0 + l15) * 64 + kc * 32 + quad * 8);

    const unsigned short* mrow[4];
#pragma unroll
    for (int reg = 0; reg < 4; reg++)
        mrow[reg] = mask + (size_t)(row0 + quad * 4 + reg) * NN;

    f32x4 Oa[4];
#pragma unroll
    for (int dt = 0; dt < 4; dt++) Oa[dt] = (f32x4){0.f, 0.f, 0.f, 0.f};
    float mrun[4], lrun[4];
#pragma unroll
    for (int r = 0; r < 4; r++) { mrun[r] = -1e30f; lrun[r] = 0.f; }

    unsigned short* Pw = Plds + w * (16 * 88);

    for (int mt = 0; mt < 8; mt++) {
        int m0 = sp * 512 + mt * 64;
        f32x4 s4[4];
#pragma unroll
        for (int t = 0; t < 4; t++) s4[t] = (f32x4){0.f, 0.f, 0.f, 0.f};
#pragma unroll
        for (int t = 0; t < 4; t++)
#pragma unroll
            for (int kc = 0; kc < 2; kc++) {
                bf16x8 kf = *(const bf16x8*)(Kb + (size_t)(m0 + t * 16 + l15) * 64 + kc * 32 + quad * 8);
                s4[t] = mfma16(qf[kc], kf, s4[t]);
            }
        bf16x8 vf[8];
#pragma unroll
        for (int dt = 0; dt < 4; dt++)
#pragma unroll
            for (int kc = 0; kc < 2; kc++)
                vf[dt * 2 + kc] = *(const bf16x8*)(Vb + (size_t)(dt * 16 + l15) * NN + m0 + kc * 32 + quad * 8);
        float mv[4][4];
#pragma unroll
        for (int t = 0; t < 4; t++)
#pragma unroll
            for (int reg = 0; reg < 4; reg++)
                mv[t][reg] = bf2f(mrow[reg][m0 + t * 16 + l15]);

        float sv[4][4], rmax[4];
#pragma unroll
        for (int r = 0; r < 4; r++) rmax[r] = -1e30f;
#pragma unroll
        for (int t = 0; t < 4; t++)
#pragma unroll
            for (int reg = 0; reg < 4; reg++) {
                float v = s4[t][reg] * mv[t][reg];   // q already scaled
                sv[t][reg] = v;
                rmax[reg] = fmaxf(rmax[reg], v);
            }
#pragma unroll
        for (int reg = 0; reg < 4; reg++) {
            rmax[reg] = fmaxf(rmax[reg], __shfl_xor(rmax[reg], 1, 64));
            rmax[reg] = fmaxf(rmax[reg], __shfl_xor(rmax[reg], 2, 64));
            rmax[reg] = fmaxf(rmax[reg], __shfl_xor(rmax[reg], 4, 64));
            rmax[reg] = fmaxf(rmax[reg], __shfl_xor(rmax[reg], 8, 64));
        }
        float alpha[4], rsum[4];
#pragma unroll
        for (int reg = 0; reg < 4; reg++) {
            float mn = fmaxf(mrun[reg], rmax[reg]);
            alpha[reg] = __expf(mrun[reg] - mn);
            mrun[reg] = mn;
            rsum[reg] = 0.f;
        }
#pragma unroll
        for (int t = 0; t < 4; t++)
#pragma unroll
            for (int reg = 0; reg < 4; reg++) {
                float p = __expf(sv[t][reg] - mrun[reg]);
                sv[t][reg] = p;
                rsum[reg] += p;
            }
#pragma unroll
        for (int reg = 0; reg < 4; reg++) {
            rsum[reg] += __shfl_xor(rsum[reg], 1, 64);
            rsum[reg] += __shfl_xor(rsum[reg], 2, 64);
            rsum[reg] += __shfl_xor(rsum[reg], 4, 64);
            rsum[reg] += __shfl_xor(rsum[reg], 8, 64);
            lrun[reg] = lrun[reg] * alpha[reg] + rsum[reg];
        }
#pragma unroll
        for (int dt = 0; dt < 4; dt++)
#pragma unroll
            for (int reg = 0; reg < 4; reg++) Oa[dt][reg] *= alpha[reg];
#pragma unroll
        for (int t = 0; t < 4; t++)
#pragma unroll
            for (int reg = 0; reg < 4; reg++)
                Pw[(quad * 4 + reg) * 88 + t * 16 + l15] = f2bf(sv[t][reg]);
        bf16x8 pf[2];
#pragma unroll
        for (int kc = 0; kc < 2; kc++)
            pf[kc] = *(const bf16x8*)(Pw + l15 * 88 + kc * 32 + quad * 8);
#pragma unroll
        for (int dt = 0; dt < 4; dt++)
#pragma unroll
            for (int kc = 0; kc < 2; kc++)
                Oa[dt] = mfma16(pf[kc], vf[dt * 2 + kc], Oa[dt]);
    }
    __syncthreads();   // phase change: Plds -> OL
    float* mine = OL + (size_t)(w * 64 + lane) * 25;
#pragma unroll
    for (int dt = 0; dt < 4; dt++)
#pragma unroll
        for (int reg = 0; reg < 4; reg++) mine[dt * 4 + reg] = Oa[dt][reg];
#pragma unroll
    for (int reg = 0; reg < 4; reg++) { mine[16 + reg] = mrun[reg]; mine[20 + reg] = lrun[reg]; }
    __syncthreads();
    if (sp == 0) {
        const float* p0 = OL + (size_t)(w * 64 + lane) * 25;
        const float* p1 = OL + (size_t)((w + 4) * 64 + lane) * 25;
        float e0[4], e1[4], li[4];
#pragma unroll
        for (int reg = 0; reg < 4; reg++) {
            float m0v = p0[16 + reg], m1v = p1[16 + reg];
            float M = fmaxf(m0v, m1v);
            e0[reg] = __expf(m0v - M);
            e1[reg] = __expf(m1v - M);
            li[reg] = 1.f / (p0[20 + reg] * e0[reg] + p1[20 + reg] * e1[reg]);
        }
#pragma unroll
        for (int dt = 0; dt < 4; dt++)
#pragma unroll
            for (int reg = 0; reg < 4; reg++) {
                float val = (p0[dt * 4 + reg] * e0[reg] + p1[dt * 4 + reg] * e1[reg]) * li[reg];
                int n = row0 + quad * 4 + reg;
                int col = h * 64 + dt * 16 + l15;   // [h*64+d] layout, matches W1m_perm
                xattn[((size_t)bb * NN + n) * DD + col] = f2bf(val);
            }
    }
}

// ---------------- conv1 = W1[:, :256]*x + W1m*attn + bmix, fused BN stats ----------------
__global__ __launch_bounds__(256) void conv1_kernel(
    const unsigned short* __restrict__ xbf, const unsigned short* __restrict__ xattn,
    const unsigned short* __restrict__ W1_l, const unsigned short* __restrict__ W1m_l,
    const float* __restrict__ bmix_l,
    unsigned short* __restrict__ out1, float* __restrict__ bnsumm) {
    int bb = blockIdx.z;
    int n0 = blockIdx.x * 64, o0 = blockIdx.y * 64;
    int w = threadIdx.x >> 6, lane = threadIdx.x & 63, quad = lane >> 4, l15 = lane & 15;
    int wr = (w & 1) * 32, wc = (w >> 1) * 32;
    const unsigned short* A1 = xbf + (size_t)bb * NN * DD + (size_t)(n0 + wr + l15) * DD + quad * 8;
    const unsigned short* A2 = xattn + (size_t)bb * NN * DD + (size_t)(n0 + wr + l15) * DD + quad * 8;
    const unsigned short* Wa = W1_l + (size_t)(o0 + wc + l15) * 512 + quad * 8;
    const unsigned short* Wb = W1m_l + (size_t)(o0 + wc + l15) * DD + quad * 8;
    f32x4 acc[2][2];
#pragma unroll
    for (int r = 0; r < 2; r++)
#pragma unroll
        for (int c = 0; c < 2; c++) acc[r][c] = (f32x4){0.f, 0.f, 0.f, 0.f};

    auto ldA = [&](int s, int rs) -> bf16x8 {
        return (s < 8) ? *(const bf16x8*)(A1 + rs * 16 * DD + s * 32)
                       : *(const bf16x8*)(A2 + rs * 16 * DD + (s - 8) * 32);
    };
    auto ldB = [&](int s, int cs) -> bf16x8 {
        return (s < 8) ? *(const bf16x8*)(Wa + cs * 16 * 512 + s * 32)
                       : *(const bf16x8*)(Wb + cs * 16 * DD + (s - 8) * 32);
    };
    bf16x8 a0 = ldA(0, 0), a1 = ldA(0, 1), b0 = ldB(0, 0), b1 = ldB(0, 1);
    bf16x8 a0n, a1n, b0n, b1n;
#pragma unroll
    for (int s = 0; s < 16; s++) {
        if (s < 15) { a0n = ldA(s + 1, 0); a1n = ldA(s + 1, 1); b0n = ldB(s + 1, 0); b1n = ldB(s + 1, 1); }
        acc[0][0] = mfma16(a0, b0, acc[0][0]);
        acc[0][1] = mfma16(a0, b1, acc[0][1]);
        acc[1][0] = mfma16(a1, b0, acc[1][0]);
        acc[1][1] = mfma16(a1, b1, acc[1][1]);
        if (s < 15) { a0 = a0n; a1 = a1n; b0 = b0n; b1 = b1n; }
    }
    __shared__ float redS[4][32], redQ[4][32];
    float cs_s[2] = {0.f, 0.f}, cs_q[2] = {0.f, 0.f};
#pragma unroll
    for (int rs = 0; rs < 2; rs++)
#pragma unroll
        for (int cs = 0; cs < 2; cs++)
#pragma unroll
            for (int reg = 0; reg < 4; reg++) {
                int n = n0 + wr + rs * 16 + quad * 4 + reg;
                int o = o0 + wc + cs * 16 + l15;
                float val = acc[rs][cs][reg] + bmix_l[o];
                out1[((size_t)bb * NN + n) * 512 + o] = f2bf(val);
                cs_s[cs] += val;
                cs_q[cs] += val * val;
            }
#pragma unroll
    for (int cs = 0; cs < 2; cs++) {
        cs_s[cs] += __shfl_down(cs_s[cs], 32, 64);
        cs_s[cs] += __shfl_down(cs_s[cs], 16, 64);
        cs_q[cs] += __shfl_down(cs_q[cs], 32, 64);
        cs_q[cs] += __shfl_down(cs_q[cs], 16, 64);
    }
    if (lane < 16) {
#pragma unroll
        for (int cs = 0; cs < 2; cs++) {
            redS[w][cs * 16 + l15] = cs_s[cs];
            redQ[w][cs * 16 + l15] = cs_q[cs];
        }
    }
    __syncthreads();
    if (threadIdx.x < 64) {
        int c = threadIdx.x;
        int p = (c < 32) ? 0 : 2;
        int ci = c & 31;
        atomicAdd(&bnsumm[o0 + c], redS[p][ci] + redS[p + 1][ci]);
        atomicAdd(&bnsumm[512 + o0 + c], redQ[p][ci] + redQ[p + 1][ci]);
    }
}

// ---------------- conv2: fused BN-finalize + BN+ReLU on A, residual epilogue ----------------
__global__ __launch_bounds__(256) void conv2_kernel(
    const unsigned short* __restrict__ out1, const unsigned short* __restrict__ W2_l,
    const float* __restrict__ b2_l, const float* __restrict__ bnsumm,
    const float* __restrict__ g1_l, const float* __restrict__ beta1_l,
    float* __restrict__ desc, unsigned short* __restrict__ xbf) {
    __shared__ float ssc[512], ssh[512];
    for (int i = threadIdx.x; i < 512; i += 256) {
        float s = bnsumm[i], s2 = bnsumm[512 + i];
        float mean = s * (1.f / 4096.f);
        float var = s2 * (1.f / 4096.f) - mean * mean;
        float sc = g1_l[i] * rsqrtf(var + 1e-5f);
        ssc[i] = sc;
        ssh[i] = beta1_l[i] - mean * sc;
    }
    __syncthreads();
    int bb = blockIdx.z;
    int n0 = blockIdx.x * 32, o0 = blockIdx.y * 64;
    int w = threadIdx.x >> 6, lane = threadIdx.x & 63, quad = lane >> 4, l15 = lane & 15;
    int wr = (w & 1) * 16, wc = (w >> 1) * 32;
    const unsigned short* Ab = out1 + ((size_t)bb * NN + n0 + wr + l15) * 512 + quad * 8;
    const unsigned short* Wb = W2_l + (size_t)(o0 + wc + l15) * 512 + quad * 8;
    f32x4 acc[2];
    acc[0] = (f32x4){0.f, 0.f, 0.f, 0.f};
    acc[1] = (f32x4){0.f, 0.f, 0.f, 0.f};

    auto ldA = [&](int s) -> bf16x8 {
        union { bf16x8 v; unsigned short u[8]; } in, o8;
        in.v = *(const bf16x8*)(Ab + s * 32);
        int kb = s * 32 + quad * 8;
#pragma unroll
        for (int j = 0; j < 8; j++)
            o8.u[j] = f2bf(fmaxf(0.f, bf2f(in.u[j]) * ssc[kb + j] + ssh[kb + j]));
        return o8.v;
    };

    bf16x8 a0 = ldA(0);
    bf16x8 b0 = *(const bf16x8*)(Wb);
    bf16x8 b1 = *(const bf16x8*)(Wb + 16 * 512);
    bf16x8 a0n, b0n, b1n;
#pragma unroll
    for (int s = 0; s < 16; s++) {
        if (s < 15) {
            int kk = (s + 1) * 32;
            a0n = ldA(s + 1);
            b0n = *(const bf16x8*)(Wb + kk);
            b1n = *(const bf16x8*)(Wb + 16 * 512 + kk);
        }
        acc[0] = mfma16(a0, b0, acc[0]);
        acc[1] = mfma16(a0, b1, acc[1]);
        if (s < 15) { a0 = a0n; b0 = b0n; b1 = b1n; }
    }
#pragma unroll
    for (int cs = 0; cs < 2; cs++)
#pragma unroll
        for (int reg = 0; reg < 4; reg++) {
            int n = n0 + wr + quad * 4 + reg;
            int o = o0 + wc + cs * 16 + l15;
            size_t di = ((size_t)bb * NN + n) * DD + o;
            float nd = desc[di] + acc[cs][reg] + b2_l[o];
            desc[di] = nd;
            xbf[di] = f2bf(nd);
        }
}

extern "C" void kernel_launch(void* const* d_in, const int* in_sizes, int n_in,
                              void* d_out, int out_size, void* d_ws, size_t ws_size,
                              hipStream_t stream) {
    const float* desc0 = (const float*)d_in[0];
    const float* desc1 = (const float*)d_in[1];
    const float* M0p   = (const float*)d_in[2];
    const float* M1p   = (const float*)d_in[3];
    const float* Wq = (const float*)d_in[4];  const float* bq = (const float*)d_in[5];
    const float* Wk = (const float*)d_in[6];  const float* bk = (const float*)d_in[7];
    const float* Wv = (const float*)d_in[8];  const float* bv = (const float*)d_in[9];
    const float* Wm = (const float*)d_in[10]; const float* bm = (const float*)d_in[11];
    const float* W1 = (const float*)d_in[12]; const float* b1 = (const float*)d_in[13];
    const float* g1 = (const float*)d_in[14]; const float* beta1 = (const float*)d_in[15];
    const float* W2 = (const float*)d_in[16]; const float* b2 = (const float*)d_in[17];
    float* out = (float*)d_out;
    char* ws = (char*)d_ws;

    float*          desc   = (float*)(ws);                               // 4 MB
    unsigned short* xbf    = (unsigned short*)(ws + (4ull << 20));       // 2 MB
    unsigned short* qb     = (unsigned short*)(ws + (6ull << 20));       // 2 MB
    unsigned short* kbuf   = (unsigned short*)(ws + (8ull << 20));       // 2 MB
    unsigned short* vbuf   = (unsigned short*)(ws + (10ull << 20));      // 2 MB
    unsigned short* xattn  = (unsigned short*)(ws + (12ull << 20));      // 2 MB
    unsigned short* out1   = (unsigned short*)(ws + (14ull << 20));      // 4 MB (bf16)
    float*          bnsumm = (float*)(ws + (18ull << 20));               // 4 KB
    float*          bmix   = (float*)(ws + (18ull << 20) + 8192);        // 12 KB
    unsigned short* maskbf = (unsigned short*)(ws + (19ull << 20));      // 8 MB
    unsigned short* W1m    = (unsigned short*)(ws + (27ull << 20));      // 1.5 MB
    unsigned short* wbf    = (unsigned short*)(ws + (29ull << 20));      // 7.5 MB

    const int SQ = LL * 65536;

    wconv_kernel<<<15360, 256, 0, stream>>>(Wq, Wk, Wv, Wm, W1, W2, wbf);
    init_kernel<<<4096, 256, 0, stream>>>(desc0, desc1, desc, xbf);
    maskconv_kernel<<<4096, 256, 0, stream>>>(M0p, M1p, maskbf);
    fold1_kernel<<<dim3(8, 4, 6), 256, 0, stream>>>(wbf + 4 * (size_t)SQ, wbf + 3 * (size_t)SQ, W1m);
    fold2_kernel<<<768, 256, 0, stream>>>(W1, bm, b1, bmix);

    for (int l = 0; l < LL; l++) {
        int cross = l & 1;
        const unsigned short* Wq_l = wbf + (size_t)l * 65536;
        const unsigned short* Wk_l = wbf + SQ + (size_t)l * 65536;
        const unsigned short* Wv_l = wbf + 2 * (size_t)SQ + (size_t)l * 65536;
        const unsigned short* W1_l = wbf + 4 * (size_t)SQ + (size_t)l * 262144;
        const unsigned short* W2_l = wbf + 4 * (size_t)SQ + (size_t)LL * 262144 + (size_t)l * 131072;
        const unsigned short* W1m_l = W1m + (size_t)l * 131072;

        proj_kernel<<<dim3(16, 4, 12), 256, 0, stream>>>(
            xbf, Wq_l, Wk_l, Wv_l, bq + l * 256, bk + l * 256, bv + l * 256,
            qb, kbuf, vbuf, cross);
        flash_kernel<<<dim3(16, 16), 512, 0, stream>>>(qb, kbuf, vbuf, maskbf, xattn, bnsumm);
        conv1_kernel<<<dim3(16, 8, 4), 256, 0, stream>>>(
            xbf, xattn, W1_l, W1m_l, bmix + l * 512, out1, bnsumm);
        conv2_kernel<<<dim3(32, 4, 4), 256, 0, stream>>>(
            out1, W2_l, b2 + l * 256, bnsumm, g1 + l * 512, beta1 + l * 512, desc, xbf);
    }

    final_kernel<<<4096, 256, 0, stream>>>(desc, out);
}

// Round 5
// 624.803 us; speedup vs baseline: 1.4840x; 1.0121x over previous
//
#include <hip/hip_runtime.h>
#include <hip/hip_bf16.h>

#define NN 1024
#define DD 256
#define LL 6

typedef __attribute__((ext_vector_type(8))) short bf16x8;
typedef __attribute__((ext_vector_type(4))) float f32x4;
typedef __attribute__((ext_vector_type(4))) unsigned short u16x4;

__device__ __forceinline__ unsigned short f2bf(float f) {
    union { float f; unsigned u; } x; x.f = f;
    return (unsigned short)((x.u + 0x7fffu + ((x.u >> 16) & 1u)) >> 16);
}

__device__ __forceinline__ float bf2f(unsigned short u) {
    union { unsigned u; float f; } x; x.u = ((unsigned)u) << 16; return x.f;
}

__device__ __forceinline__ f32x4 mfma16(bf16x8 a, bf16x8 b, f32x4 c) {
    return __builtin_amdgcn_mfma_f32_16x16x32_bf16(a, b, c, 0, 0, 0);
}

// ---------------- weight fp32 -> bf16 conversion; q/k/v rows permuted to o'=h*64+d ----
__global__ void wconv_kernel(const float* __restrict__ Wq, const float* __restrict__ Wk,
                             const float* __restrict__ Wv, const float* __restrict__ Wm,
                             const float* __restrict__ W1, const float* __restrict__ W2,
                             unsigned short* __restrict__ dst) {
    const int SQ = LL * 65536;
    const int S1 = LL * 262144;
    int idx = blockIdx.x * 256 + threadIdx.x;
    int total = 4 * SQ + S1 + LL * 131072;
    if (idx >= total) return;
    float v;
    if (idx < 4 * SQ) {
        int seg = idx / SQ, off = idx % SQ;
        const float* p = (seg == 0) ? Wq : (seg == 1) ? Wk : (seg == 2) ? Wv : Wm;
        if (seg < 3) {
            int l = off >> 16, rem = off & 65535;
            int op = rem >> 8, i = rem & 255;          // op = h*64+d
            int src = ((op & 63) << 2) | (op >> 6);    // d*4+h
            v = p[(size_t)l * 65536 + src * 256 + i];
        } else {
            v = p[off];
        }
    } else if (idx < 4 * SQ + S1) {
        v = W1[idx - 4 * SQ];
    } else {
        v = W2[idx - 4 * SQ - S1];
    }
    dst[idx] = f2bf(v);
}

// ---------------- mask fp32 -> bf16 ----------------
__global__ void maskconv_kernel(const float* __restrict__ M0, const float* __restrict__ M1,
                                unsigned short* __restrict__ mbf) {
    int idx = blockIdx.x * 256 + threadIdx.x;
    size_t base = (size_t)idx * 4;
    int bb = (int)(base >> 20);
    const float* src = (bb < 2) ? (M0 + base) : (M1 + base - (2ull << 20));
    f32x4 v = *(const f32x4*)src;
    u16x4 o;
#pragma unroll
    for (int j = 0; j < 4; j++) o[j] = f2bf(v[j]);
    *(u16x4*)(mbf + base) = o;
}

// ---------------- fold1 (MFMA): W1m_perm[l][o][h*64+d] ----------------
__global__ __launch_bounds__(256) void fold1_kernel(const unsigned short* __restrict__ W1bf,
                                                    const unsigned short* __restrict__ Wmbf,
                                                    unsigned short* __restrict__ W1m) {
    int l = blockIdx.z;
    int o0 = blockIdx.x * 64, i0 = blockIdx.y * 64;
    const unsigned short* A = W1bf + (size_t)l * 262144;
    const unsigned short* B = Wmbf + (size_t)l * 65536;
    __shared__ unsigned short Bt[64][264];
    int t = threadIdx.x;
#pragma unroll
    for (int r = 0; r < 8; r++) {
        int j = r * 32 + (t >> 3);
        int il = (t & 7) * 8;
        union { bf16x8 v; unsigned short u[8]; } ld;
        ld.v = *(const bf16x8*)(B + (size_t)j * 256 + i0 + il);
#pragma unroll
        for (int jj = 0; jj < 8; jj++) Bt[il + jj][j] = ld.u[jj];
    }
    __syncthreads();
    int w = t >> 6, lane = t & 63, quad = lane >> 4, l15 = lane & 15;
    int wr = (w & 1) * 32, wc = (w >> 1) * 32;
    const unsigned short* Ab = A + (size_t)(o0 + wr + l15) * 512 + 256 + quad * 8;
    f32x4 acc[2][2];
#pragma unroll
    for (int r = 0; r < 2; r++)
#pragma unroll
        for (int c = 0; c < 2; c++) acc[r][c] = (f32x4){0.f, 0.f, 0.f, 0.f};
#pragma unroll
    for (int s = 0; s < 8; s++) {
        int kk = s * 32;
        bf16x8 a0 = *(const bf16x8*)(Ab + kk);
        bf16x8 a1 = *(const bf16x8*)(Ab + 16 * 512 + kk);
        bf16x8 b0 = *(const bf16x8*)(&Bt[wc + l15][kk + quad * 8]);
        bf16x8 b1 = *(const bf16x8*)(&Bt[wc + 16 + l15][kk + quad * 8]);
        acc[0][0] = mfma16(a0, b0, acc[0][0]);
        acc[0][1] = mfma16(a0, b1, acc[0][1]);
        acc[1][0] = mfma16(a1, b0, acc[1][0]);
        acc[1][1] = mfma16(a1, b1, acc[1][1]);
    }
#pragma unroll
    for (int rs = 0; rs < 2; rs++)
#pragma unroll
        for (int cs = 0; cs < 2; cs++)
#pragma unroll
            for (int reg = 0; reg < 4; reg++) {
                int o = o0 + wr + rs * 16 + quad * 4 + reg;
                int i = i0 + wc + cs * 16 + l15;
                int pc = (i & 3) * 64 + (i >> 2);
                W1m[((size_t)l * 512 + o) * 256 + pc] = f2bf(acc[rs][cs][reg]);
            }
}

// ---------------- fold2 ----------------
__global__ __launch_bounds__(256) void fold2_kernel(const float* __restrict__ W1,
                                                    const float* __restrict__ bm,
                                                    const float* __restrict__ b1,
                                                    float* __restrict__ bmix) {
    int wid = blockIdx.x * 4 + (threadIdx.x >> 6);
    int lane = threadIdx.x & 63;
    int l = wid >> 9, o = wid & 511;
    const float* row = W1 + ((size_t)l * 512 + o) * 512 + 256;
    const float* bmr = bm + (size_t)l * 256;
    f32x4 r = *(const f32x4*)(row + lane * 4);
    f32x4 bb4 = *(const f32x4*)(bmr + lane * 4);
    float acc = r[0] * bb4[0] + r[1] * bb4[1] + r[2] * bb4[2] + r[3] * bb4[3];
    acc += __shfl_xor(acc, 1, 64);
    acc += __shfl_xor(acc, 2, 64);
    acc += __shfl_xor(acc, 4, 64);
    acc += __shfl_xor(acc, 8, 64);
    acc += __shfl_xor(acc, 16, 64);
    acc += __shfl_xor(acc, 32, 64);
    if (lane == 0) bmix[wid] = b1[wid] + acc;
}

// ---------------- init: [2][256][1024] -> [4][1024][256] via LDS tiles ----------------
__global__ __launch_bounds__(256) void init_kernel(const float* __restrict__ desc0,
                                                   const float* __restrict__ desc1,
                                                   float* __restrict__ desc,
                                                   unsigned short* __restrict__ xbf) {
    __shared__ float T[32][33];
    int bb = blockIdx.z;
    int n0 = blockIdx.x * 32, c0 = blockIdx.y * 32;
    const float* src = (bb < 2) ? (desc0 + (size_t)bb * DD * NN)
                                : (desc1 + (size_t)(bb - 2) * DD * NN);
    int i = threadIdx.x >> 5, j = threadIdx.x & 31;
#pragma unroll
    for (int r = 0; r < 4; r++) {
        int c = i + r * 8;
        T[c][j] = src[(size_t)(c0 + c) * NN + n0 + j];
    }
    __syncthreads();
#pragma unroll
    for (int r = 0; r < 4; r++) {
        int n = i + r * 8;
        float v = T[j][n];
        size_t di = ((size_t)bb * NN + n0 + n) * DD + c0 + j;
        desc[di] = v;
        xbf[di] = f2bf(v);
    }
}

// ---------------- final: [4][1024][256] -> [4][256][1024] via LDS tiles ----------------
__global__ __launch_bounds__(256) void final_kernel(const float* __restrict__ desc,
                                                    float* __restrict__ out) {
    __shared__ float T[32][33];
    int bb = blockIdx.z;
    int n0 = blockIdx.x * 32, c0 = blockIdx.y * 32;
    int i = threadIdx.x >> 5, j = threadIdx.x & 31;
#pragma unroll
    for (int r = 0; r < 4; r++) {
        int n = i + r * 8;
        T[n][j] = desc[((size_t)bb * NN + n0 + n) * DD + c0 + j];
    }
    __syncthreads();
#pragma unroll
    for (int r = 0; r < 4; r++) {
        int c = i + r * 8;
        out[((size_t)bb * DD + c0 + c) * NN + n0 + j] = T[j][c];
    }
}

// ---------------- q/k/v projections: permuted W, LDS-staged coalesced epilogue -------
// q,k -> [bb][n][o'=h*64+d] ; v -> [bh][d][n]
__global__ __launch_bounds__(256) void proj_kernel(
    const unsigned short* __restrict__ xbf,
    const unsigned short* __restrict__ Wq_l, const unsigned short* __restrict__ Wk_l,
    const unsigned short* __restrict__ Wv_l,
    const float* __restrict__ bq_l, const float* __restrict__ bk_l,
    const float* __restrict__ bv_l,
    unsigned short* __restrict__ qb, unsigned short* __restrict__ kb,
    unsigned short* __restrict__ vb, int cross) {
    __shared__ unsigned short St[64][72];
    int z = blockIdx.z;
    int bb = z / 3, mat = z % 3;
    int srcbb = (mat == 0) ? bb : (cross ? (bb ^ 2) : bb);
    const unsigned short* A = xbf + (size_t)srcbb * NN * DD;
    const unsigned short* W = (mat == 0) ? Wq_l : (mat == 1) ? Wk_l : Wv_l;
    const float* bias = (mat == 0) ? bq_l : (mat == 1) ? bk_l : bv_l;
    int n0 = blockIdx.x * 64, o0 = blockIdx.y * 64;
    int w = threadIdx.x >> 6, lane = threadIdx.x & 63, quad = lane >> 4, l15 = lane & 15;
    int wr = (w & 1) * 32, wc = (w >> 1) * 32;
    const unsigned short* Ab = A + (size_t)(n0 + wr + l15) * DD + quad * 8;
    const unsigned short* Wb = W + (size_t)(o0 + wc + l15) * DD + quad * 8;
    f32x4 acc[2][2];
#pragma unroll
    for (int r = 0; r < 2; r++)
#pragma unroll
        for (int c = 0; c < 2; c++) acc[r][c] = (f32x4){0.f, 0.f, 0.f, 0.f};
    bf16x8 a0, a1, b0, b1, a0n, a1n, b0n, b1n;
    a0 = *(const bf16x8*)(Ab);
    a1 = *(const bf16x8*)(Ab + 16 * DD);
    b0 = *(const bf16x8*)(Wb);
    b1 = *(const bf16x8*)(Wb + 16 * DD);
#pragma unroll
    for (int s = 0; s < 8; s++) {
        if (s < 7) {
            int kk = (s + 1) * 32;
            a0n = *(const bf16x8*)(Ab + kk);
            a1n = *(const bf16x8*)(Ab + 16 * DD + kk);
            b0n = *(const bf16x8*)(Wb + kk);
            b1n = *(const bf16x8*)(Wb + 16 * DD + kk);
        }
        acc[0][0] = mfma16(a0, b0, acc[0][0]);
        acc[0][1] = mfma16(a0, b1, acc[0][1]);
        acc[1][0] = mfma16(a1, b0, acc[1][0]);
        acc[1][1] = mfma16(a1, b1, acc[1][1]);
        if (s < 7) { a0 = a0n; a1 = a1n; b0 = b0n; b1 = b1n; }
    }
    float qscale = (mat == 0) ? 0.125f : 1.0f;
#pragma unroll
    for (int rs = 0; rs < 2; rs++)
#pragma unroll
        for (int cs = 0; cs < 2; cs++) {
            int op = o0 + wc + cs * 16 + l15;                // o' = h*64+d
            float bv4 = bias[((op & 63) << 2) | (op >> 6)];  // source index d*4+h
#pragma unroll
            for (int reg = 0; reg < 4; reg++) {
                int nl = wr + rs * 16 + quad * 4 + reg;
                int ol = wc + cs * 16 + l15;
                unsigned short val = f2bf((acc[rs][cs][reg] + bv4) * qscale);
                if (mat < 2) St[nl][ol] = val;
                else St[ol][nl] = val;
            }
        }
    __syncthreads();
    int r = threadIdx.x >> 2, cb = (threadIdx.x & 3) * 16;
    bf16x8 v0 = *(const bf16x8*)(&St[r][cb]);
    bf16x8 v1 = *(const bf16x8*)(&St[r][cb + 8]);
    if (mat < 2) {
        unsigned short* dst = ((mat == 0) ? qb : kb) + ((size_t)bb * NN + n0 + r) * 256 + o0 + cb;
        *(bf16x8*)(dst) = v0;
        *(bf16x8*)(dst + 8) = v1;
    } else {
        int op = o0 + r;
        unsigned short* dst = vb + ((size_t)(bb * 4 + (op >> 6)) * 64 + (op & 63)) * NN + n0 + cb;
        *(bf16x8*)(dst) = v0;
        *(bf16x8*)(dst + 8) = v1;
    }
}

// ---------------- flash attention: 512 blocks x 8 waves, 4-way m-split ----------------
__global__ __launch_bounds__(512, 4) void flash_kernel(
    const unsigned short* __restrict__ qb, const unsigned short* __restrict__ kb,
    const unsigned short* __restrict__ vb,
    const unsigned short* __restrict__ maskbf,
    unsigned short* __restrict__ xattn, float* __restrict__ bnsumm) {
    __shared__ __align__(16) char smem[51200];
    unsigned short* Plds = (unsigned short*)smem;   // phase 1: [8][16][40]
    float* OL = (float*)smem;                        // phase 2: [8][64][25]

    int bh = blockIdx.y, nb = blockIdx.x;            // nb 0..31
    int bb = bh >> 2, h = bh & 3;
    int tid = threadIdx.x, w = tid >> 6, lane = tid & 63, quad = lane >> 4, l15 = lane & 15;
    int qg = w & 1, sp = w >> 1;

    if (nb == 0 && bh == 0) { bnsumm[tid] = 0.f; bnsumm[tid + 512] = 0.f; }

    const unsigned short* mask = maskbf + (size_t)bb * NN * NN;
    const unsigned short* Q = qb + (size_t)bb * NN * 256 + h * 64;
    const unsigned short* Kb = kb + (size_t)bb * NN * 256 + h * 64;
    const unsigned short* Vb = vb + (size_t)bh * 64 * NN;
    int row0 = nb * 32 + qg * 16;

    bf16x8 qf[2];
#pragma unroll
    for (int kc = 0; kc < 2; kc++)
        qf[kc] = *(const bf16x8*)(Q + (size_t)(row0 + l15) * 256 + kc * 32 + quad * 8);

    const unsigned short* mrow[4];
#pragma unroll
    for (int reg = 0; reg < 4; reg++)
        mrow[reg] = mask + (size_t)(row0 + quad * 4 + reg) * NN + sp * 256;

    f32x4 Oa[4];
#pragma unroll
    for (int dt = 0; dt < 4; dt++) Oa[dt] = (f32x4){0.f, 0.f, 0.f, 0.f};
    float mrun[4], lrun[4];
#pragma unroll
    for (int r = 0; r < 4; r++) { mrun[r] = -1e30f; lrun[r] = 0.f; }

    unsigned short* Pw = Plds + w * (16 * 40);

    // prefetch mask for tile 0
    float mv[2][4];
#pragma unroll
    for (int t = 0; t < 2; t++)
#pragma unroll
        for (int reg = 0; reg < 4; reg++)
            mv[t][reg] = bf2f(mrow[reg][t * 16 + l15]);

    for (int mt = 0; mt < 8; mt++) {
        int m0 = sp * 256 + mt * 32;
        int mloc = mt * 32;
        f32x4 s4[2];
        s4[0] = (f32x4){0.f, 0.f, 0.f, 0.f};
        s4[1] = (f32x4){0.f, 0.f, 0.f, 0.f};
#pragma unroll
        for (int t = 0; t < 2; t++)
#pragma unroll
            for (int kc = 0; kc < 2; kc++) {
                bf16x8 kf = *(const bf16x8*)(Kb + (size_t)(m0 + t * 16 + l15) * 256 + kc * 32 + quad * 8);
                s4[t] = mfma16(qf[kc], kf, s4[t]);
            }
        // V loads (k=32 per frag)
        bf16x8 vf[4];
#pragma unroll
        for (int dt = 0; dt < 4; dt++)
            vf[dt] = *(const bf16x8*)(Vb + (size_t)(dt * 16 + l15) * NN + m0 + quad * 8);
        // next-tile mask prefetch
        float mvn[2][4];
        if (mt < 7) {
#pragma unroll
            for (int t = 0; t < 2; t++)
#pragma unroll
                for (int reg = 0; reg < 4; reg++)
                    mvn[t][reg] = bf2f(mrow[reg][mloc + 32 + t * 16 + l15]);
        }
        // online softmax over 8 elems/lane
        float sv[2][4], rmax[4];
#pragma unroll
        for (int r = 0; r < 4; r++) rmax[r] = -1e30f;
#pragma unroll
        for (int t = 0; t < 2; t++)
#pragma unroll
            for (int reg = 0; reg < 4; reg++) {
                float v = s4[t][reg] * mv[t][reg];
                sv[t][reg] = v;
                rmax[reg] = fmaxf(rmax[reg], v);
            }
#pragma unroll
        for (int reg = 0; reg < 4; reg++) {
            rmax[reg] = fmaxf(rmax[reg], __shfl_xor(rmax[reg], 1, 64));
            rmax[reg] = fmaxf(rmax[reg], __shfl_xor(rmax[reg], 2, 64));
            rmax[reg] = fmaxf(rmax[reg], __shfl_xor(rmax[reg], 4, 64));
            rmax[reg] = fmaxf(rmax[reg], __shfl_xor(rmax[reg], 8, 64));
        }
        float alpha[4], rsum[4];
#pragma unroll
        for (int reg = 0; reg < 4; reg++) {
            float mn = fmaxf(mrun[reg], rmax[reg]);
            alpha[reg] = __expf(mrun[reg] - mn);
            mrun[reg] = mn;
            rsum[reg] = 0.f;
        }
#pragma unroll
        for (int t = 0; t < 2; t++)
#pragma unroll
            for (int reg = 0; reg < 4; reg++) {
                float p = __expf(sv[t][reg] - mrun[reg]);
                sv[t][reg] = p;
                rsum[reg] += p;
            }
#pragma unroll
        for (int reg = 0; reg < 4; reg++) {
            rsum[reg] += __shfl_xor(rsum[reg], 1, 64);
            rsum[reg] += __shfl_xor(rsum[reg], 2, 64);
            rsum[reg] += __shfl_xor(rsum[reg], 4, 64);
            rsum[reg] += __shfl_xor(rsum[reg], 8, 64);
            lrun[reg] = lrun[reg] * alpha[reg] + rsum[reg];
        }
#pragma unroll
        for (int dt = 0; dt < 4; dt++)
#pragma unroll
            for (int reg = 0; reg < 4; reg++) Oa[dt][reg] *= alpha[reg];
        // P: C-layout -> A-layout via per-wave LDS
#pragma unroll
        for (int t = 0; t < 2; t++)
#pragma unroll
            for (int reg = 0; reg < 4; reg++)
                Pw[(quad * 4 + reg) * 40 + t * 16 + l15] = f2bf(sv[t][reg]);
        bf16x8 pf = *(const bf16x8*)(Pw + l15 * 40 + quad * 8);
#pragma unroll
        for (int dt = 0; dt < 4; dt++)
            Oa[dt] = mfma16(pf, vf[dt], Oa[dt]);
        if (mt < 7) {
#pragma unroll
            for (int t = 0; t < 2; t++)
#pragma unroll
                for (int reg = 0; reg < 4; reg++) mv[t][reg] = mvn[t][reg];
        }
    }
    __syncthreads();   // phase change: Plds -> OL
    float* mine = OL + (size_t)(w * 64 + lane) * 25;
#pragma unroll
    for (int dt = 0; dt < 4; dt++)
#pragma unroll
        for (int reg = 0; reg < 4; reg++) mine[dt * 4 + reg] = Oa[dt][reg];
#pragma unroll
    for (int reg = 0; reg < 4; reg++) { mine[16 + reg] = mrun[reg]; mine[20 + reg] = lrun[reg]; }
    __syncthreads();
    if (sp == 0) {
        const float* p[4];
#pragma unroll
        for (int j = 0; j < 4; j++) p[j] = OL + (size_t)((qg + 2 * j) * 64 + lane) * 25;
        float e[4][4], li[4];
#pragma unroll
        for (int reg = 0; reg < 4; reg++) {
            float M = fmaxf(fmaxf(p[0][16 + reg], p[1][16 + reg]),
                            fmaxf(p[2][16 + reg], p[3][16 + reg]));
            float L = 0.f;
#pragma unroll
            for (int j = 0; j < 4; j++) {
                e[j][reg] = __expf(p[j][16 + reg] - M);
                L += p[j][20 + reg] * e[j][reg];
            }
            li[reg] = 1.f / L;
        }
#pragma unroll
        for (int dt = 0; dt < 4; dt++)
#pragma unroll
            for (int reg = 0; reg < 4; reg++) {
                float val = 0.f;
#pragma unroll
                for (int j = 0; j < 4; j++) val += p[j][dt * 4 + reg] * e[j][reg];
                val *= li[reg];
                int n = row0 + quad * 4 + reg;
                int col = h * 64 + dt * 16 + l15;
                xattn[((size_t)bb * NN + n) * DD + col] = f2bf(val);
            }
    }
}

// ---------------- conv1 = W1[:, :256]*x + W1m*attn + bmix, fused BN stats ----------------
__global__ __launch_bounds__(256) void conv1_kernel(
    const unsigned short* __restrict__ xbf, const unsigned short* __restrict__ xattn,
    const unsigned short* __restrict__ W1_l, const unsigned short* __restrict__ W1m_l,
    const float* __restrict__ bmix_l,
    unsigned short* __restrict__ out1, float* __restrict__ bnsumm) {
    int bb = blockIdx.z;
    int n0 = blockIdx.x * 64, o0 = blockIdx.y * 64;
    int w = threadIdx.x >> 6, lane = threadIdx.x & 63, quad = lane >> 4, l15 = lane & 15;
    int wr = (w & 1) * 32, wc = (w >> 1) * 32;
    const unsigned short* A1 = xbf + (size_t)bb * NN * DD + (size_t)(n0 + wr + l15) * DD + quad * 8;
    const unsigned short* A2 = xattn + (size_t)bb * NN * DD + (size_t)(n0 + wr + l15) * DD + quad * 8;
    const unsigned short* Wa = W1_l + (size_t)(o0 + wc + l15) * 512 + quad * 8;
    const unsigned short* Wb = W1m_l + (size_t)(o0 + wc + l15) * DD + quad * 8;
    f32x4 acc[2][2];
#pragma unroll
    for (int r = 0; r < 2; r++)
#pragma unroll
        for (int c = 0; c < 2; c++) acc[r][c] = (f32x4){0.f, 0.f, 0.f, 0.f};

    auto ldA = [&](int s, int rs) -> bf16x8 {
        return (s < 8) ? *(const bf16x8*)(A1 + rs * 16 * DD + s * 32)
                       : *(const bf16x8*)(A2 + rs * 16 * DD + (s - 8) * 32);
    };
    auto ldB = [&](int s, int cs) -> bf16x8 {
        return (s < 8) ? *(const bf16x8*)(Wa + cs * 16 * 512 + s * 32)
                       : *(const bf16x8*)(Wb + cs * 16 * DD + (s - 8) * 32);
    };
    bf16x8 a0 = ldA(0, 0), a1 = ldA(0, 1), b0 = ldB(0, 0), b1 = ldB(0, 1);
    bf16x8 a0n, a1n, b0n, b1n;
#pragma unroll
    for (int s = 0; s < 16; s++) {
        if (s < 15) { a0n = ldA(s + 1, 0); a1n = ldA(s + 1, 1); b0n = ldB(s + 1, 0); b1n = ldB(s + 1, 1); }
        acc[0][0] = mfma16(a0, b0, acc[0][0]);
        acc[0][1] = mfma16(a0, b1, acc[0][1]);
        acc[1][0] = mfma16(a1, b0, acc[1][0]);
        acc[1][1] = mfma16(a1, b1, acc[1][1]);
        if (s < 15) { a0 = a0n; a1 = a1n; b0 = b0n; b1 = b1n; }
    }
    __shared__ float redS[4][32], redQ[4][32];
    float cs_s[2] = {0.f, 0.f}, cs_q[2] = {0.f, 0.f};
#pragma unroll
    for (int rs = 0; rs < 2; rs++)
#pragma unroll
        for (int cs = 0; cs < 2; cs++)
#pragma unroll
            for (int reg = 0; reg < 4; reg++) {
                int n = n0 + wr + rs * 16 + quad * 4 + reg;
                int o = o0 + wc + cs * 16 + l15;
                float val = acc[rs][cs][reg] + bmix_l[o];
                out1[((size_t)bb * NN + n) * 512 + o] = f2bf(val);
                cs_s[cs] += val;
                cs_q[cs] += val * val;
            }
#pragma unroll
    for (int cs = 0; cs < 2; cs++) {
        cs_s[cs] += __shfl_down(cs_s[cs], 32, 64);
        cs_s[cs] += __shfl_down(cs_s[cs], 16, 64);
        cs_q[cs] += __shfl_down(cs_q[cs], 32, 64);
        cs_q[cs] += __shfl_down(cs_q[cs], 16, 64);
    }
    if (lane < 16) {
#pragma unroll
        for (int cs = 0; cs < 2; cs++) {
            redS[w][cs * 16 + l15] = cs_s[cs];
            redQ[w][cs * 16 + l15] = cs_q[cs];
        }
    }
    __syncthreads();
    if (threadIdx.x < 64) {
        int c = threadIdx.x;
        int p = (c < 32) ? 0 : 2;
        int ci = c & 31;
        atomicAdd(&bnsumm[o0 + c], redS[p][ci] + redS[p + 1][ci]);
        atomicAdd(&bnsumm[512 + o0 + c], redQ[p][ci] + redQ[p + 1][ci]);
    }
}

// ---------------- conv2: fused BN-finalize + BN+ReLU on A, residual epilogue ----------------
__global__ __launch_bounds__(256) void conv2_kernel(
    const unsigned short* __restrict__ out1, const unsigned short* __restrict__ W2_l,
    const float* __restrict__ b2_l, const float* __restrict__ bnsumm,
    const float* __restrict__ g1_l, const float* __restrict__ beta1_l,
    float* __restrict__ desc, unsigned short* __restrict__ xbf) {
    __shared__ float ssc[512], ssh[512];
    for (int i = threadIdx.x; i < 512; i += 256) {
        float s = bnsumm[i], s2 = bnsumm[512 + i];
        float mean = s * (1.f / 4096.f);
        float var = s2 * (1.f / 4096.f) - mean * mean;
        float sc = g1_l[i] * rsqrtf(var + 1e-5f);
        ssc[i] = sc;
        ssh[i] = beta1_l[i] - mean * sc;
    }
    __syncthreads();
    int bb = blockIdx.z;
    int n0 = blockIdx.x * 32, o0 = blockIdx.y * 64;
    int w = threadIdx.x >> 6, lane = threadIdx.x & 63, quad = lane >> 4, l15 = lane & 15;
    int wr = (w & 1) * 16, wc = (w >> 1) * 32;
    const unsigned short* Ab = out1 + ((size_t)bb * NN + n0 + wr + l15) * 512 + quad * 8;
    const unsigned short* Wb = W2_l + (size_t)(o0 + wc + l15) * 512 + quad * 8;
    f32x4 acc[2];
    acc[0] = (f32x4){0.f, 0.f, 0.f, 0.f};
    acc[1] = (f32x4){0.f, 0.f, 0.f, 0.f};

    auto ldA = [&](int s) -> bf16x8 {
        union { bf16x8 v; unsigned short u[8]; } in, o8;
        in.v = *(const bf16x8*)(Ab + s * 32);
        int kb = s * 32 + quad * 8;
#pragma unroll
        for (int j = 0; j < 8; j++)
            o8.u[j] = f2bf(fmaxf(0.f, bf2f(in.u[j]) * ssc[kb + j] + ssh[kb + j]));
        return o8.v;
    };

    bf16x8 a0 = ldA(0);
    bf16x8 b0 = *(const bf16x8*)(Wb);
    bf16x8 b1 = *(const bf16x8*)(Wb + 16 * 512);
    bf16x8 a0n, b0n, b1n;
#pragma unroll
    for (int s = 0; s < 16; s++) {
        if (s < 15) {
            int kk = (s + 1) * 32;
            a0n = ldA(s + 1);
            b0n = *(const bf16x8*)(Wb + kk);
            b1n = *(const bf16x8*)(Wb + 16 * 512 + kk);
        }
        acc[0] = mfma16(a0, b0, acc[0]);
        acc[1] = mfma16(a0, b1, acc[1]);
        if (s < 15) { a0 = a0n; b0 = b0n; b1 = b1n; }
    }
#pragma unroll
    for (int cs = 0; cs < 2; cs++)
#pragma unroll
        for (int reg = 0; reg < 4; reg++) {
            int n = n0 + wr + quad * 4 + reg;
            int o = o0 + wc + cs * 16 + l15;
            size_t di = ((size_t)bb * NN + n) * DD + o;
            float nd = desc[di] + acc[cs][reg] + b2_l[o];
            desc[di] = nd;
            xbf[di] = f2bf(nd);
        }
}

extern "C" void kernel_launch(void* const* d_in, const int* in_sizes, int n_in,
                              void* d_out, int out_size, void* d_ws, size_t ws_size,
                              hipStream_t stream) {
    const float* desc0 = (const float*)d_in[0];
    const float* desc1 = (const float*)d_in[1];
    const float* M0p   = (const float*)d_in[2];
    const float* M1p   = (const float*)d_in[3];
    const float* Wq = (const float*)d_in[4];  const float* bq = (const float*)d_in[5];
    const float* Wk = (const float*)d_in[6];  const float* bk = (const float*)d_in[7];
    const float* Wv = (const float*)d_in[8];  const float* bv = (const float*)d_in[9];
    const float* Wm = (const float*)d_in[10]; const float* bm = (const float*)d_in[11];
    const float* W1 = (const float*)d_in[12]; const float* b1 = (const float*)d_in[13];
    const float* g1 = (const float*)d_in[14]; const float* beta1 = (const float*)d_in[15];
    const float* W2 = (const float*)d_in[16]; const float* b2 = (const float*)d_in[17];
    float* out = (float*)d_out;
    char* ws = (char*)d_ws;

    float*          desc   = (float*)(ws);                               // 4 MB
    unsigned short* xbf    = (unsigned short*)(ws + (4ull << 20));       // 2 MB
    unsigned short* qb     = (unsigned short*)(ws + (6ull << 20));       // 2 MB
    unsigned short* kbuf   = (unsigned short*)(ws + (8ull << 20));       // 2 MB
    unsigned short* vbuf   = (unsigned short*)(ws + (10ull << 20));      // 2 MB
    unsigned short* xattn  = (unsigned short*)(ws + (12ull << 20));      // 2 MB
    unsigned short* out1   = (unsigned short*)(ws + (14ull << 20));      // 4 MB (bf16)
    float*          bnsumm = (float*)(ws + (18ull << 20));               // 4 KB
    float*          bmix   = (float*)(ws + (18ull << 20) + 8192);        // 12 KB
    unsigned short* maskbf = (unsigned short*)(ws + (19ull << 20));      // 8 MB
    unsigned short* W1m    = (unsigned short*)(ws + (27ull << 20));      // 1.5 MB
    unsigned short* wbf    = (unsigned short*)(ws + (29ull << 20));      // 7.5 MB

    const int SQ = LL * 65536;

    wconv_kernel<<<15360, 256, 0, stream>>>(Wq, Wk, Wv, Wm, W1, W2, wbf);
    init_kernel<<<dim3(32, 8, 4), 256, 0, stream>>>(desc0, desc1, desc, xbf);
    maskconv_kernel<<<4096, 256, 0, stream>>>(M0p, M1p, maskbf);
    fold1_kernel<<<dim3(8, 4, 6), 256, 0, stream>>>(wbf + 4 * (size_t)SQ, wbf + 3 * (size_t)SQ, W1m);
    fold2_kernel<<<768, 256, 0, stream>>>(W1, bm, b1, bmix);

    for (int l = 0; l < LL; l++) {
        int cross = l & 1;
        const unsigned short* Wq_l = wbf + (size_t)l * 65536;
        const unsigned short* Wk_l = wbf + SQ + (size_t)l * 65536;
        const unsigned short* Wv_l = wbf + 2 * (size_t)SQ + (size_t)l * 65536;
        const unsigned short* W1_l = wbf + 4 * (size_t)SQ + (size_t)l * 262144;
        const unsigned short* W2_l = wbf + 4 * (size_t)SQ + (size_t)LL * 262144 + (size_t)l * 131072;
        const unsigned short* W1m_l = W1m + (size_t)l * 131072;

        proj_kernel<<<dim3(16, 4, 12), 256, 0, stream>>>(
            xbf, Wq_l, Wk_l, Wv_l, bq + l * 256, bk + l * 256, bv + l * 256,
            qb, kbuf, vbuf, cross);
        flash_kernel<<<dim3(32, 16), 512, 0, stream>>>(qb, kbuf, vbuf, maskbf, xattn, bnsumm);
        conv1_kernel<<<dim3(16, 8, 4), 256, 0, stream>>>(
            xbf, xattn, W1_l, W1m_l, bmix + l * 512, out1, bnsumm);
        conv2_kernel<<<dim3(32, 4, 4), 256, 0, stream>>>(
            out1, W2_l, b2 + l * 256, bnsumm, g1 + l * 512, beta1 + l * 512, desc, xbf);
    }

    final_kernel<<<dim3(32, 8, 4), 256, 0, stream>>>(desc, out);
}